// Round 4
// baseline (1213.884 us; speedup 1.0000x reference)
//
#include <hip/hip_runtime.h>
#include <hip/hip_bf16.h>

#define DM 512
#define NH 8
#define DK 64
#define SEQ 512
#define NB 8
#define NL 6
#define DFF 2048
#define OUTD 1000
#define EMB_SCALE 22.627416997969522f
#define PE_C (-0.017988946039015984f)   // -ln(10000)/512

typedef __bf16 bf16x8 __attribute__((ext_vector_type(8)));
typedef __bf16 bf16x4 __attribute__((ext_vector_type(4)));
typedef float f32x4 __attribute__((ext_vector_type(4)));

__device__ __forceinline__ void load16_lds(const __bf16* g, __bf16* l) {
  __builtin_amdgcn_global_load_lds(
      (const __attribute__((address_space(1))) void*)g,
      (__attribute__((address_space(3))) void*)l, 16, 0, 0);
}

__device__ __forceinline__ float dot8(bf16x8 w, const float* a) {
  float s = 0.f;
#pragma unroll
  for (int j = 0; j < 8; ++j) s += (float)w[j] * a[j];
  return s;
}

// ---------------- PE table ----------------
__global__ __launch_bounds__(256) void pe_kernel(float* __restrict__ pe) {
  int s = blockIdx.x;
  int d2 = threadIdx.x;
  float div = expf((float)(2 * d2) * PE_C);
  float arg = (float)s * div;
  pe[(size_t)s * DM + 2 * d2] = sinf(arg);
  pe[(size_t)s * DM + 2 * d2 + 1] = cosf(arg);
}

// ---------------- embedding ----------------
__global__ __launch_bounds__(256) void embed_enc(const int* __restrict__ x,
                                                 const float* __restrict__ emb,
                                                 const float* __restrict__ pe,
                                                 float* __restrict__ e,
                                                 __bf16* __restrict__ eb) {
  int idx = blockIdx.x * 256 + threadIdx.x;
  int d = idx & (DM - 1);
  int bs = idx >> 9;
  int s = bs & (SEQ - 1);
  int tok = x[bs];
  float v = emb[(size_t)tok * DM + d] * EMB_SCALE + pe[(size_t)s * DM + d];
  e[idx] = v;
  eb[idx] = (__bf16)v;
}

__global__ __launch_bounds__(256) void embed_dec(const int* __restrict__ t,
                                                 const float* __restrict__ emb,
                                                 float* __restrict__ dd) {
  int idx = blockIdx.x * 256 + threadIdx.x;
  int d = idx & (DM - 1);
  int b = idx >> 9;
  float pe = (d & 1) ? 1.0f : 0.0f;
  dd[idx] = emb[(size_t)t[b] * DM + d] * EMB_SCALE + pe;
}

// ---------------- weight transpose fp32[K][N] -> bf16[N][K] ----------------
__global__ __launch_bounds__(256) void transpose_w(const float* __restrict__ W,
                                                   __bf16* __restrict__ WT,
                                                   int K, int N) {
  __shared__ float t[32][33];
  size_t off = (size_t)blockIdx.z * K * N;
  W += off; WT += off;
  int k0 = blockIdx.y * 32, n0 = blockIdx.x * 32;
  int tx = threadIdx.x & 7, ty = threadIdx.x >> 3;
  float4 v = *(const float4*)&W[(size_t)(k0 + ty) * N + n0 + tx * 4];
  t[ty][tx * 4 + 0] = v.x; t[ty][tx * 4 + 1] = v.y;
  t[ty][tx * 4 + 2] = v.z; t[ty][tx * 4 + 3] = v.w;
  __syncthreads();
  bf16x4 o;
  o[0] = (__bf16)t[tx * 4 + 0][ty];
  o[1] = (__bf16)t[tx * 4 + 1][ty];
  o[2] = (__bf16)t[tx * 4 + 2][ty];
  o[3] = (__bf16)t[tx * 4 + 3][ty];
  *(bf16x4*)&WT[(size_t)(n0 + ty) * K + k0 + tx * 4] = o;
}

// out_w fp32 [512][1000] -> bf16 [1000][512] (guarded tail)
__global__ __launch_bounds__(256) void transpose_ow(const float* __restrict__ W,
                                                    __bf16* __restrict__ WT) {
  __shared__ float t[32][33];
  int n0 = blockIdx.x * 32, k0 = blockIdx.y * 32;
  int tid = threadIdx.x;
  for (int i = tid; i < 1024; i += 256) {
    int kk = i >> 5, nn = i & 31;
    t[kk][nn] = (n0 + nn < OUTD) ? W[(size_t)(k0 + kk) * OUTD + n0 + nn] : 0.f;
  }
  __syncthreads();
  for (int i = tid; i < 1024; i += 256) {
    int nn = i >> 5, kk = i & 31;
    if (n0 + nn < OUTD)
      WT[(size_t)(n0 + nn) * DM + k0 + kk] = (__bf16)t[kk][nn];
  }
}

// ---------------- MFMA GEMM: 256 thr / 4 waves, BM=128 x BN=64 tile,
// depth-2 prefetch, 3 LDS buffers, counted s_waitcnt vmcnt(6) (T4).
// Loads for tile t+1 get a full iteration of compute to land; the barrier
// never drains vmcnt to 0 in steady state. LDS 72KB -> 2 blocks/CU.
// SK>1: split-K, partial z!=0 written to C + z*cStride; combined in add_ln.
template <int BN, int SK, bool RELU, bool WF32, bool WBF16, bool TRV, bool KVM>
__global__ __launch_bounds__(256) void mfma_gemm(
    const __bf16* __restrict__ A, const __bf16* __restrict__ BT,
    const float* __restrict__ bias, float* __restrict__ C,
    __bf16* __restrict__ Cb, __bf16* __restrict__ Vt, int M, int N, int K,
    long btStride, long bStride, long cStride) {
  static_assert(BN == 64, "vmcnt literal assumes 6 loads per stage");
  // XCD swizzle: each XCD owns a contiguous y-chunk; x fastest, z slowest.
  int gx = gridDim.x, gy = gridDim.y;
  int lin = blockIdx.x + gx * (blockIdx.y + gy * blockIdx.z);
  int xcd = lin & 7, li = lin >> 3;
  int yc = gy >> 3;
  int bx = li % gx;
  int t2 = li / gx;
  int by = xcd * yc + (t2 % yc);
  int z = t2 / yc;

  if (SK == 1) {
    if (KVM) {
      long idx = (long)(z >> 1) * 3 + 1 + (z & 1);
      BT += idx * btStride;
      bias += idx * bStride;
    } else {
      BT += (size_t)z * btStride;
      bias += (size_t)z * bStride;
    }
  }
  if (WF32) C += (size_t)z * cStride;
  if (WBF16) Cb += (size_t)z * cStride;

  constexpr int NI = BN / 32;
  __shared__ __bf16 As[3][128 * 64];
  __shared__ __bf16 Bs[3][BN * 64];

  int tid = threadIdx.x;
  int wave = tid >> 6, lane = tid & 63;
  int wm = wave >> 1, wn = wave & 1;           // 2 x 2 wave grid
  int quad = lane >> 4, l16 = lane & 15;
  int rlane = lane >> 3, c8 = lane & 7;
  int m0 = by * 128, n0 = bx * BN;
  int gcol = ((c8 ^ rlane) * 8);

  f32x4 acc[4][NI];
#pragma unroll
  for (int i = 0; i < 4; ++i)
#pragma unroll
    for (int j = 0; j < NI; ++j) acc[i][j] = (f32x4){0.f, 0.f, 0.f, 0.f};

  auto stage = [&](int buf, int k0) {   // 6 global_load_lds per thread
#pragma unroll
    for (int j = 0; j < 4; ++j) {
      int rb = j * 32 + wave * 8;
      load16_lds(&A[(size_t)(m0 + rb + rlane) * K + k0 + gcol],
                 &As[buf][rb * 64]);
    }
#pragma unroll
    for (int j = 0; j < BN / 32; ++j) {
      int rb = j * 32 + wave * 8;
      load16_lds(&BT[(size_t)(n0 + rb + rlane) * K + k0 + gcol],
                 &Bs[buf][rb * 64]);
    }
  };

  int kLen = (SK > 1) ? (K / SK) : K;
  int kBeg = (SK > 1) ? z * kLen : 0;
  const int NT = kLen >> 6;

  // prologue: fill pipe two deep
  stage(0, kBeg);
  if (NT > 1) {
    stage(1, kBeg + 64);
    asm volatile("s_waitcnt vmcnt(6)" ::: "memory");
  } else {
    asm volatile("s_waitcnt vmcnt(0)" ::: "memory");
  }
  __builtin_amdgcn_s_barrier();
  __builtin_amdgcn_sched_barrier(0);

  int cur = 0;
  for (int t = 0; t < NT; ++t) {
    if (t + 2 < NT) {
      int tgt = cur + 2; if (tgt >= 3) tgt -= 3;
      stage(tgt, kBeg + ((t + 2) << 6));
    }
#pragma unroll
    for (int kk = 0; kk < 64; kk += 32) {
      bf16x8 af[4], bfr[NI];
#pragma unroll
      for (int i = 0; i < 4; ++i) {
        int row = wm * 64 + i * 16 + l16;
        af[i] = *(const bf16x8*)&As[cur][row * 64 + ((((kk >> 3) + quad) ^ (row & 7)) * 8)];
      }
#pragma unroll
      for (int i = 0; i < NI; ++i) {
        int row = wn * (BN / 2) + i * 16 + l16;
        bfr[i] = *(const bf16x8*)&Bs[cur][row * 64 + ((((kk >> 3) + quad) ^ (row & 7)) * 8)];
      }
#pragma unroll
      for (int mi = 0; mi < 4; ++mi)
#pragma unroll
        for (int ni = 0; ni < NI; ++ni)
          acc[mi][ni] = __builtin_amdgcn_mfma_f32_16x16x32_bf16(
              af[mi], bfr[ni], acc[mi][ni], 0, 0, 0);
    }
    if (t + 1 < NT) {
      if (t + 2 < NT)
        asm volatile("s_waitcnt vmcnt(6) lgkmcnt(0)" ::: "memory");
      else
        asm volatile("s_waitcnt vmcnt(0) lgkmcnt(0)" ::: "memory");
      __builtin_amdgcn_s_barrier();
      __builtin_amdgcn_sched_barrier(0);
    }
    ++cur; if (cur == 3) cur = 0;
  }

#pragma unroll
  for (int ni = 0; ni < NI; ++ni) {
    int col = n0 + wn * (BN / 2) + ni * 16 + l16;
    float bv = (SK == 1 || z == 0) ? bias[col] : 0.f;
    if (TRV && z == 2) {
      int b = m0 >> 9;
#pragma unroll
      for (int mi = 0; mi < 4; ++mi) {
        int srow = (m0 & 511) + wm * 64 + mi * 16 + quad * 4;
        bf16x4 pk;
#pragma unroll
        for (int r = 0; r < 4; ++r) pk[r] = (__bf16)(acc[mi][ni][r] + bv);
        *(bf16x4*)&Vt[((size_t)(b * 512 + col)) * 512 + srow] = pk;
      }
    } else {
#pragma unroll
      for (int mi = 0; mi < 4; ++mi) {
#pragma unroll
        for (int r = 0; r < 4; ++r) {
          int row = m0 + wm * 64 + mi * 16 + quad * 4 + r;
          float v = acc[mi][ni][r] + bv;
          if (RELU) v = fmaxf(v, 0.f);
          if (WF32) C[(size_t)row * N + col] = v;
          if (WBF16) Cb[(size_t)row * N + col] = (__bf16)v;
        }
      }
    }
  }
}

// ---------------- MFMA encoder attention: depth-2 prefetch, counted vmcnt --
#define SCP 520
__global__ __launch_bounds__(256) void attn_mfma(const __bf16* __restrict__ QKV,
                                                 const __bf16* __restrict__ Vt,
                                                 float* __restrict__ O) {
  __shared__ __bf16 Sc[16 * SCP];
  __shared__ __bf16 Tt[3][64 * 64];

  const long ACTL = (long)NB * SEQ * DM;
  int tid = threadIdx.x;
  int wave = tid >> 6, lane = tid & 63;
  int quad = lane >> 4, l16 = lane & 15;
  int rlane = lane >> 3, c8 = lane & 7;
  // XCD swizzle: chunk by bh so each XCD's L2 holds few K/V panels.
  int lin = blockIdx.x + gridDim.x * blockIdx.y;
  int xcd = lin & 7, li = lin >> 3;
  int yc = gridDim.y >> 3;
  int q0 = (li % gridDim.x) * 16;
  int bh = xcd * yc + li / gridDim.x;
  int b = bh >> 3, h = bh & 7;
  const __bf16* Q = QKV;
  const __bf16* Kp = QKV + ACTL;
  size_t baseQ = ((size_t)b * SEQ + q0) * DM + h * DK;
  size_t baseK = ((size_t)b * SEQ) * DM + h * DK;
  const __bf16* VtB = Vt + ((size_t)(b * 512 + h * 64)) * 512;
  int gcol = (c8 ^ rlane) * 8;

  bf16x8 af0 = *(const bf16x8*)&Q[baseQ + (size_t)l16 * DM + quad * 8];
  bf16x8 af1 = *(const bf16x8*)&Q[baseQ + (size_t)l16 * DM + 32 + quad * 8];

  auto stageK = [&](int buf, int kt) {   // 2 loads per thread
#pragma unroll
    for (int j = 0; j < 2; ++j) {
      int row = j * 32 + wave * 8 + rlane;
      load16_lds(&Kp[baseK + (size_t)(kt * 64 + row) * DM + gcol],
                 &Tt[buf][(j * 32 + wave * 8) * 64]);
    }
  };
  auto stageV = [&](int buf, int kt) {   // 2 loads per thread
#pragma unroll
    for (int j = 0; j < 2; ++j) {
      int row = j * 32 + wave * 8 + rlane;
      load16_lds(&VtB[(size_t)row * 512 + kt * 64 + gcol],
                 &Tt[buf][(j * 32 + wave * 8) * 64]);
    }
  };

  // ---- QK^T, 8 tiles, depth-2 prefetch ----
  stageK(0, 0);
  stageK(1, 1);
  asm volatile("s_waitcnt vmcnt(2)" ::: "memory");
  __builtin_amdgcn_s_barrier();
  __builtin_amdgcn_sched_barrier(0);
#pragma unroll
  for (int kt = 0; kt < 8; ++kt) {
    if (kt + 2 < 8) stageK((kt + 2) % 3, kt + 2);
    f32x4 acc = (f32x4){0.f, 0.f, 0.f, 0.f};
    int krow = wave * 16 + l16, sw = krow & 7;
    bf16x8 b0 = *(const bf16x8*)&Tt[kt % 3][krow * 64 + ((quad ^ sw) * 8)];
    bf16x8 b1 = *(const bf16x8*)&Tt[kt % 3][krow * 64 + (((4 + quad) ^ sw) * 8)];
    acc = __builtin_amdgcn_mfma_f32_16x16x32_bf16(af0, b0, acc, 0, 0, 0);
    acc = __builtin_amdgcn_mfma_f32_16x16x32_bf16(af1, b1, acc, 0, 0, 0);
#pragma unroll
    for (int r = 0; r < 4; ++r)
      Sc[(quad * 4 + r) * SCP + kt * 64 + wave * 16 + l16] =
          (__bf16)(acc[r] * 0.125f);
    if (kt < 7) {
      if (kt + 2 < 8)
        asm volatile("s_waitcnt vmcnt(2) lgkmcnt(0)" ::: "memory");
      else
        asm volatile("s_waitcnt vmcnt(0) lgkmcnt(0)" ::: "memory");
      __builtin_amdgcn_s_barrier();
      __builtin_amdgcn_sched_barrier(0);
    }
  }
  __syncthreads();   // Sc visible to all waves; all Tt reads complete

  // prefetch first two V tiles; they land under the softmax
  stageV(0, 0);
  stageV(1, 1);

  // ---- softmax over 16 rows ----
#pragma unroll
  for (int rr = 0; rr < 4; ++rr) {
    int r = wave * 4 + rr;
    float v[8];
    float mx = -1e30f;
#pragma unroll
    for (int j = 0; j < 8; ++j) {
      v[j] = (float)Sc[r * SCP + j * 64 + lane];
      mx = fmaxf(mx, v[j]);
    }
    for (int o = 32; o > 0; o >>= 1) mx = fmaxf(mx, __shfl_xor(mx, o));
    float sum = 0.f;
#pragma unroll
    for (int j = 0; j < 8; ++j) { v[j] = __expf(v[j] - mx); sum += v[j]; }
    for (int o = 32; o > 0; o >>= 1) sum += __shfl_xor(sum, o);
    float inv = 1.f / sum;
#pragma unroll
    for (int j = 0; j < 8; ++j)
      Sc[r * SCP + j * 64 + lane] = (__bf16)(v[j] * inv);
  }
  asm volatile("s_waitcnt vmcnt(2) lgkmcnt(0)" ::: "memory");  // V0 ready, Sc drained
  __builtin_amdgcn_s_barrier();
  __builtin_amdgcn_sched_barrier(0);

  // ---- PV, 8 tiles, depth-2 prefetch ----
  f32x4 oacc = (f32x4){0.f, 0.f, 0.f, 0.f};
#pragma unroll
  for (int kt = 0; kt < 8; ++kt) {
    if (kt + 2 < 8) stageV((kt + 2) % 3, kt + 2);
    int drow = wave * 16 + l16, sw = drow & 7;
#pragma unroll
    for (int kk = 0; kk < 64; kk += 32) {
      bf16x8 pa = *(const bf16x8*)&Sc[l16 * SCP + kt * 64 + kk + quad * 8];
      bf16x8 vb = *(const bf16x8*)&Tt[kt % 3][drow * 64 + ((((kk >> 3) + quad) ^ sw) * 8)];
      oacc = __builtin_amdgcn_mfma_f32_16x16x32_bf16(pa, vb, oacc, 0, 0, 0);
    }
    if (kt < 7) {
      if (kt + 2 < 8)
        asm volatile("s_waitcnt vmcnt(2) lgkmcnt(0)" ::: "memory");
      else
        asm volatile("s_waitcnt vmcnt(0) lgkmcnt(0)" ::: "memory");
      __builtin_amdgcn_s_barrier();
      __builtin_amdgcn_sched_barrier(0);
    }
  }
#pragma unroll
  for (int r = 0; r < 4; ++r)
    O[((size_t)b * SEQ + q0 + quad * 4 + r) * DM + h * DK + wave * 16 + l16] =
        oacc[r];
}

// ---------------- residual + layernorm (optional second summand x2) -------
template <bool WB>
__global__ __launch_bounds__(256) void add_ln(
    const float* __restrict__ x, const float* __restrict__ x2,
    const float* __restrict__ res, const float* __restrict__ cbias,
    const float* __restrict__ g, const float* __restrict__ beta,
    float* __restrict__ y, __bf16* __restrict__ yb) {
  int row = blockIdx.x;
  int tid = threadIdx.x;
  const float* xr = x + (size_t)row * DM;
  const float* rr = res + (size_t)row * DM;
  float b0 = cbias ? cbias[tid] : 0.f;
  float b1 = cbias ? cbias[tid + 256] : 0.f;
  float v0 = xr[tid] + b0 + rr[tid];
  float v1 = xr[tid + 256] + b1 + rr[tid + 256];
  if (x2) {
    const float* x2r = x2 + (size_t)row * DM;
    v0 += x2r[tid];
    v1 += x2r[tid + 256];
  }
  float s = v0 + v1, sq = v0 * v0 + v1 * v1;
  for (int o = 32; o > 0; o >>= 1) {
    s += __shfl_xor(s, o);
    sq += __shfl_xor(sq, o);
  }
  __shared__ float ps[4], pq[4];
  int wv = tid >> 6;
  if ((tid & 63) == 0) { ps[wv] = s; pq[wv] = sq; }
  __syncthreads();
  s = ps[0] + ps[1] + ps[2] + ps[3];
  sq = pq[0] + pq[1] + pq[2] + pq[3];
  float mean = s * (1.f / DM);
  float var = sq * (1.f / DM) - mean * mean;
  float rstd = rsqrtf(var + 1e-5f);
  float o0 = (v0 - mean) * rstd * g[tid] + beta[tid];
  float o1 = (v1 - mean) * rstd * g[tid + 256] + beta[tid + 256];
  y[(size_t)row * DM + tid] = o0;
  y[(size_t)row * DM + tid + 256] = o1;
  if (WB) {
    yb[(size_t)row * DM + tid] = (__bf16)o0;
    yb[(size_t)row * DM + tid + 256] = (__bf16)o1;
  }
}

// ============ fused decoder kernels (M = 8 rows) ============

// dd[r] = LN(dd[r] + dd[r] @ WvT^T + bv)  -- one block per row
__global__ __launch_bounds__(256) void dec_vln(
    float* __restrict__ dd, const __bf16* __restrict__ WvT,
    const float* __restrict__ bv, const float* __restrict__ g,
    const float* __restrict__ beta) {
  __shared__ float arow[DM];
  int r = blockIdx.x, tid = threadIdx.x;
  arow[tid] = dd[(size_t)r * DM + tid];
  arow[tid + 256] = dd[(size_t)r * DM + tid + 256];
  __syncthreads();
  float out[2];
#pragma unroll
  for (int cc = 0; cc < 2; ++cc) {
    int c = tid + cc * 256;
    const __bf16* w = &WvT[(size_t)c * DM];
    float acc = 0.f;
#pragma unroll 4
    for (int k = 0; k < DM; k += 8) acc += dot8(*(const bf16x8*)&w[k], &arow[k]);
    out[cc] = arow[c] + acc + bv[c];
  }
  float s = out[0] + out[1], sq = out[0] * out[0] + out[1] * out[1];
  for (int o = 32; o > 0; o >>= 1) { s += __shfl_xor(s, o); sq += __shfl_xor(sq, o); }
  __shared__ float ps[4], pq[4];
  int wv = tid >> 6;
  if ((tid & 63) == 0) { ps[wv] = s; pq[wv] = sq; }
  __syncthreads();
  s = ps[0] + ps[1] + ps[2] + ps[3];
  sq = pq[0] + pq[1] + pq[2] + pq[3];
  float mean = s * (1.f / DM);
  float rstd = rsqrtf(sq * (1.f / DM) - mean * mean + 1e-5f);
  dd[(size_t)r * DM + tid] = (out[0] - mean) * rstd * g[tid] + beta[tid];
  dd[(size_t)r * DM + tid + 256] = (out[1] - mean) * rstd * g[tid + 256] + beta[tid + 256];
}

// q = dd[b] @ Wq[:,h*64..] + bq; attention over 512 bf16 keys/values -> da
// one block per (b,h)
__global__ __launch_bounds__(256) void dec_qattn(
    const float* __restrict__ dd, const __bf16* __restrict__ WqT,
    const float* __restrict__ qb, const __bf16* __restrict__ Kb,
    const __bf16* __restrict__ Vb, float* __restrict__ da) {
  __shared__ float arow[DM];
  __shared__ float red[4][64];
  __shared__ float q[64];
  __shared__ float sc[SEQ];
  __shared__ float wred[4];

  int bh = blockIdx.x, b = bh >> 3, h = bh & 7;
  int tid = threadIdx.x, lane = tid & 63, wave = tid >> 6;
  arow[tid] = dd[(size_t)b * DM + tid];
  arow[tid + 256] = dd[(size_t)b * DM + tid + 256];
  __syncthreads();

  // q-gemv: 64 cols x 4 k-subs
  {
    int c = tid & 63, s = tid >> 6;
    const __bf16* w = &WqT[(size_t)(h * 64 + c) * DM + s * 128];
    float acc = 0.f;
#pragma unroll
    for (int k = 0; k < 128; k += 8) acc += dot8(*(const bf16x8*)&w[k], &arow[s * 128 + k]);
    red[s][c] = acc;
  }
  __syncthreads();
  if (tid < 64) q[tid] = red[0][tid] + red[1][tid] + red[2][tid] + red[3][tid] + qb[h * 64 + tid];
  __syncthreads();

  // scores
  for (int key = tid; key < SEQ; key += 256) {
    const __bf16* kp = &Kb[((size_t)b * SEQ + key) * DM + h * 64];
    float acc = 0.f;
#pragma unroll
    for (int k = 0; k < 64; k += 8) acc += dot8(*(const bf16x8*)&kp[k], &q[k]);
    sc[key] = acc * 0.125f;
  }
  __syncthreads();
  float m = -1e30f;
  for (int j = tid; j < SEQ; j += 256) m = fmaxf(m, sc[j]);
  for (int o = 32; o > 0; o >>= 1) m = fmaxf(m, __shfl_xor(m, o));
  if (lane == 0) wred[wave] = m;
  __syncthreads();
  m = fmaxf(fmaxf(wred[0], wred[1]), fmaxf(wred[2], wred[3]));
  float sum = 0.f;
  for (int j = tid; j < SEQ; j += 256) {
    float p = __expf(sc[j] - m);
    sc[j] = p;
    sum += p;
  }
  for (int o = 32; o > 0; o >>= 1) sum += __shfl_xor(sum, o);
  __syncthreads();   // sc writes done before reuse of wred
  if (lane == 0) wred[wave] = sum;
  __syncthreads();
  float inv = 1.f / (wred[0] + wred[1] + wred[2] + wred[3]);

  // PV
  {
    int d = tid & 63, s = tid >> 6;
    float acc = 0.f;
    const __bf16* vp = &Vb[((size_t)b * SEQ + s * 128) * DM + h * 64 + d];
#pragma unroll 8
    for (int k = 0; k < 128; ++k) acc += sc[s * 128 + k] * (float)vp[(size_t)k * DM];
    red[s][d] = acc;
  }
  __syncthreads();
  if (tid < 64)
    da[(size_t)b * DM + h * 64 + tid] =
        (red[0][tid] + red[1][tid] + red[2][tid] + red[3][tid]) * inv;
}

// h[r][col] = relu(dd[r] @ W1T[col] + b1[col]); wave per col, 4 cols/block
__global__ __launch_bounds__(256) void dec_ffn1(
    const float* __restrict__ dd, const __bf16* __restrict__ W1T,
    const float* __restrict__ b1, float* __restrict__ h) {
  __shared__ float a[8][DM];
  int tid = threadIdx.x, lane = tid & 63, wave = tid >> 6;
  for (int i = tid; i < 8 * DM; i += 256) a[i >> 9][i & 511] = dd[i];
  __syncthreads();
  int col = blockIdx.x * 4 + wave;
  bf16x8 w = *(const bf16x8*)&W1T[(size_t)col * DM + lane * 8];
  float acc[8];
#pragma unroll
  for (int r = 0; r < 8; ++r) acc[r] = dot8(w, &a[r][lane * 8]);
#pragma unroll
  for (int r = 0; r < 8; ++r)
    for (int o = 32; o > 0; o >>= 1) acc[r] += __shfl_xor(acc[r], o);
  if (lane == 0) {
    float bb = b1[col];
#pragma unroll
    for (int r = 0; r < 8; ++r) h[(size_t)r * DFF + col] = fmaxf(acc[r] + bb, 0.f);
  }
}

// df[r][col] = h[r] @ W2T[col] + b2[col]; 2 cols/block, 2 waves per col
__global__ __launch_bounds__(256) void dec_ffn2(
    const float* __restrict__ h, const __bf16* __restrict__ W2T,
    const float* __restrict__ b2, float* __restrict__ df) {
  __shared__ float red[4][8];
  int tid = threadIdx.x, lane = tid & 63, wave = tid >> 6;
  int c = wave >> 1, half = wave & 1;
  int col = blockIdx.x * 2 + c;
  int k0 = half * 1024 + lane * 8;
  bf16x8 w0 = *(const bf16x8*)&W2T[(size_t)col * DFF + k0];
  bf16x8 w1 = *(const bf16x8*)&W2T[(size_t)col * DFF + k0 + 512];
  float acc[8];
#pragma unroll
  for (int r = 0; r < 8; ++r) {
    float4 h0a = *(const float4*)&h[(size_t)r * DFF + k0];
    float4 h0b = *(const float4*)&h[(size_t)r * DFF + k0 + 4];
    float4 h1a = *(const float4*)&h[(size_t)r * DFF + k0 + 512];
    float4 h1b = *(const float4*)&h[(size_t)r * DFF + k0 + 516];
    float hh0[8] = {h0a.x, h0a.y, h0a.z, h0a.w, h0b.x, h0b.y, h0b.z, h0b.w};
    float hh1[8] = {h1a.x, h1a.y, h1a.z, h1a.w, h1b.x, h1b.y, h1b.z, h1b.w};
    acc[r] = dot8(w0, hh0) + dot8(w1, hh1);
  }
#pragma unroll
  for (int r = 0; r < 8; ++r)
    for (int o = 32; o > 0; o >>= 1) acc[r] += __shfl_xor(acc[r], o);
  if (lane == 0) {
#pragma unroll
    for (int r = 0; r < 8; ++r) red[wave][r] = acc[r];
  }
  __syncthreads();
  if (tid < 16) {
    int cc = tid >> 3, r = tid & 7;
    int ocol = blockIdx.x * 2 + cc;
    df[(size_t)r * DM + ocol] =
        red[cc * 2][r] + red[cc * 2 + 1][r] + b2[ocol];
  }
}

// out[r][col] = dd[r] @ WoT[col] + ob[col]; wave per col, 4 cols/block
__global__ __launch_bounds__(256) void dec_out(
    const float* __restrict__ dd, const __bf16* __restrict__ WoT,
    const float* __restrict__ ob, float* __restrict__ out) {
  __shared__ float a[8][DM];
  int tid = threadIdx.x, lane = tid & 63, wave = tid >> 6;
  for (int i = tid; i < 8 * DM; i += 256) a[i >> 9][i & 511] = dd[i];
  __syncthreads();
  int col = blockIdx.x * 4 + wave;
  bf16x8 w = *(const bf16x8*)&WoT[(size_t)col * DM + lane * 8];
  float acc[8];
#pragma unroll
  for (int r = 0; r < 8; ++r) acc[r] = dot8(w, &a[r][lane * 8]);
#pragma unroll
  for (int r = 0; r < 8; ++r)
    for (int o = 32; o > 0; o >>= 1) acc[r] += __shfl_xor(acc[r], o);
  if (lane == 0) {
    float bb = ob[col];
#pragma unroll
    for (int r = 0; r < 8; ++r) out[(size_t)r * OUTD + col] = acc[r] + bb;
  }
}

// ---------------------------------------------------------------------------
extern "C" void kernel_launch(void* const* d_in, const int* in_sizes, int n_in,
                              void* d_out, int out_size, void* d_ws, size_t ws_size,
                              hipStream_t stream) {
  const int* x = (const int*)d_in[0];
  const int* target = (const int*)d_in[1];
  const float* in_emb = (const float*)d_in[2];
  const float* out_emb = (const float*)d_in[3];
  const float* enc_qkv_w = (const float*)d_in[4];
  const float* enc_qkv_b = (const float*)d_in[5];
  const float* enc_ln1_g = (const float*)d_in[6];
  const float* enc_ln1_b = (const float*)d_in[7];
  const float* enc_ffn1_w = (const float*)d_in[8];
  const float* enc_ffn1_b = (const float*)d_in[9];
  const float* enc_ffn2_w = (const float*)d_in[10];
  const float* enc_ffn2_b = (const float*)d_in[11];
  const float* enc_ln2_g = (const float*)d_in[12];
  const float* enc_ln2_b = (const float*)d_in[13];
  const float* dec_qkv1_w = (const float*)d_in[14];
  const float* dec_qkv1_b = (const float*)d_in[15];
  const float* dec_ln1_g = (const float*)d_in[16];
  const float* dec_ln1_b = (const float*)d_in[17];
  const float* dec_qkv2_w = (const float*)d_in[18];
  const float* dec_qkv2_b = (const float*)d_in[19];
  const float* dec_ln2_g = (const float*)d_in[20];
  const float* dec_ln2_b = (const float*)d_in[21];
  const float* dec_ffn1_w = (const float*)d_in[22];
  const float* dec_ffn1_b = (const float*)d_in[23];
  const float* dec_ffn2_w = (const float*)d_in[24];
  const float* dec_ffn2_b = (const float*)d_in[25];
  const float* dec_ln3_g = (const float*)d_in[26];
  const float* dec_ln3_b = (const float*)d_in[27];
  const float* out_w = (const float*)d_in[28];
  const float* out_b = (const float*)d_in[29];

  const long ACTL = (long)NB * SEQ * DM;           // 2M elems
  const int M = NB * SEQ;                           // 4096
  const long WQS = (long)DM * DM;
  const long WFS = (long)DM * DFF;

  char* p = (char*)d_ws;
  float* e = (float*)p;            p += ACTL * 4;
  float* tb = (float*)p;           p += ACTL * 4;
  float* pe = (float*)p;           p += (long)SEQ * DM * 4;
  float* dd = (float*)p;           p += NB * DM * 4;
  float* da = (float*)p;           p += NB * DM * 4;
  float* dh = (float*)p;           p += NB * DFF * 4;
  float* df = (float*)p;           p += NB * DM * 4;
  p = (char*)(((uintptr_t)p + 255) & ~(uintptr_t)255);
  __bf16* eb = (__bf16*)p;         p += ACTL * 2;
  __bf16* qkvb = (__bf16*)p;       p += 3 * ACTL * 2;   // Q,K; slice 2 = V^T
  __bf16* hbb = (__bf16*)p;        p += (long)M * DFF * 2;
  __bf16* kvb = (__bf16*)p;        p += 12L * ACTL * 2; // [layer][K,V][4096][512]
  __bf16* wtq = (__bf16*)p;        p += 18L * WQS * 2;
  __bf16* wtf1 = (__bf16*)p;       p += 6L * WFS * 2;
  __bf16* wtf2 = (__bf16*)p;       p += 6L * WFS * 2;
  __bf16* wtd = (__bf16*)p;        p += 18L * WQS * 2;  // dec_qkv2^T
  __bf16* wtd1 = (__bf16*)p;       p += 18L * WQS * 2;  // dec_qkv1^T
  __bf16* wf1t = (__bf16*)p;       p += 6L * WFS * 2;
  __bf16* wf2t = (__bf16*)p;       p += 6L * WFS * 2;
  __bf16* wot = (__bf16*)p;        p += (long)OUTD * DM * 2;

  __bf16* vtb = qkvb + 2 * ACTL;
  // split-K partial-1 for encoder FFN2: reuse kvb region (idle until the
  // KV gemm after the encoder loop)
  float* tb2 = (float*)kvb;
  long tb2Off = (long)(tb2 - tb);  // element stride from partial0 to partial1

  // ---- one-time prep ----
  pe_kernel<<<SEQ, 256, 0, stream>>>(pe);
  transpose_w<<<dim3(16, 16, 18), 256, 0, stream>>>(enc_qkv_w, wtq, DM, DM);
  transpose_w<<<dim3(64, 16, 6), 256, 0, stream>>>(enc_ffn1_w, wtf1, DM, DFF);
  transpose_w<<<dim3(16, 64, 6), 256, 0, stream>>>(enc_ffn2_w, wtf2, DFF, DM);
  transpose_w<<<dim3(16, 16, 18), 256, 0, stream>>>(dec_qkv2_w, wtd, DM, DM);
  transpose_w<<<dim3(16, 16, 18), 256, 0, stream>>>(dec_qkv1_w, wtd1, DM, DM);
  transpose_w<<<dim3(64, 16, 6), 256, 0, stream>>>(dec_ffn1_w, wf1t, DM, DFF);
  transpose_w<<<dim3(16, 64, 6), 256, 0, stream>>>(dec_ffn2_w, wf2t, DFF, DM);
  transpose_ow<<<dim3(32, 16), 256, 0, stream>>>(out_w, wot);

  // ---- encoder ----
  embed_enc<<<(M * DM) / 256, 256, 0, stream>>>(x, in_emb, pe, e, eb);
  for (int i = 0; i < NL; ++i) {
    mfma_gemm<64, 1, false, false, true, true, false><<<dim3(8, 32, 3), 256, 0, stream>>>(
        eb, wtq + (size_t)i * 3 * WQS, enc_qkv_b + (size_t)i * 3 * DM,
        nullptr, qkvb, vtb, M, DM, DM, WQS, DM, ACTL);
    attn_mfma<<<dim3(SEQ / 16, NB * NH), 256, 0, stream>>>(qkvb, vtb, tb);
    add_ln<true><<<M, 256, 0, stream>>>(tb, nullptr, e, nullptr,
                                        enc_ln1_g + i * DM, enc_ln1_b + i * DM,
                                        e, eb);
    mfma_gemm<64, 1, true, false, true, false, false><<<dim3(32, 32, 1), 256, 0, stream>>>(
        eb, wtf1 + (size_t)i * WFS, enc_ffn1_b + (size_t)i * DFF,
        nullptr, hbb, nullptr, M, DFF, DM, 0, 0, 0);
    mfma_gemm<64, 2, false, true, false, false, false><<<dim3(8, 32, 2), 256, 0, stream>>>(
        hbb, wtf2 + (size_t)i * WFS, enc_ffn2_b + (size_t)i * DM,
        tb, nullptr, nullptr, M, DM, DFF, 0, 0, tb2Off);
    add_ln<true><<<M, 256, 0, stream>>>(tb, tb2, e, nullptr,
                                        enc_ln2_g + i * DM, enc_ln2_b + i * DM,
                                        e, eb);
  }

  // ---- cross K/V for all 6 layers in one dispatch (bf16 out) ----
  mfma_gemm<64, 1, false, false, true, false, true><<<dim3(8, 32, 12), 256, 0, stream>>>(
      eb, wtd, dec_qkv2_b, nullptr, kvb, nullptr, M, DM, DM, WQS, DM, ACTL);

  // ---- decoder (seq len 1, fully fused, no atomics/memsets) ----
  embed_dec<<<(NB * DM) / 256, 256, 0, stream>>>(target, out_emb, dd);
  for (int i = 0; i < NL; ++i) {
    dec_vln<<<8, 256, 0, stream>>>(
        dd, wtd1 + ((size_t)i * 3 + 2) * WQS, dec_qkv1_b + ((size_t)i * 3 + 2) * DM,
        dec_ln1_g + i * DM, dec_ln1_b + i * DM);
    dec_qattn<<<64, 256, 0, stream>>>(
        dd, wtd + (size_t)i * 3 * WQS, dec_qkv2_b + (size_t)i * 3 * DM,
        kvb + (size_t)i * 2 * ACTL, kvb + ((size_t)i * 2 + 1) * ACTL, da);
    add_ln<false><<<NB, 256, 0, stream>>>(
        da, nullptr, dd, nullptr, dec_ln2_g + i * DM, dec_ln2_b + i * DM,
        dd, nullptr);
    dec_ffn1<<<DFF / 4, 256, 0, stream>>>(
        dd, wf1t + (size_t)i * WFS, dec_ffn1_b + (size_t)i * DFF, dh);
    dec_ffn2<<<DM / 2, 256, 0, stream>>>(
        dh, wf2t + (size_t)i * WFS, dec_ffn2_b + (size_t)i * DM, df);
    add_ln<false><<<NB, 256, 0, stream>>>(
        df, nullptr, dd, nullptr, dec_ln3_g + i * DM, dec_ln3_b + i * DM,
        dd, nullptr);
  }

  // ---- output projection (direct, bias fused) ----
  dec_out<<<OUTD / 4, 256, 0, stream>>>(dd, wot, out_b, (float*)d_out);
}

// Round 5
// 1168.361 us; speedup vs baseline: 1.0390x; 1.0390x over previous
//
#include <hip/hip_runtime.h>
#include <hip/hip_bf16.h>

#define DM 512
#define NH 8
#define DK 64
#define SEQ 512
#define NB 8
#define NL 6
#define DFF 2048
#define OUTD 1000
#define EMB_SCALE 22.627416997969522f
#define PE_C (-0.017988946039015984f)   // -ln(10000)/512

typedef __bf16 bf16x8 __attribute__((ext_vector_type(8)));
typedef __bf16 bf16x4 __attribute__((ext_vector_type(4)));
typedef float f32x4 __attribute__((ext_vector_type(4)));

__device__ __forceinline__ void load16_lds(const __bf16* g, __bf16* l) {
  __builtin_amdgcn_global_load_lds(
      (const __attribute__((address_space(1))) void*)g,
      (__attribute__((address_space(3))) void*)l, 16, 0, 0);
}

__device__ __forceinline__ float dot8(bf16x8 w, const float* a) {
  float s = 0.f;
#pragma unroll
  for (int j = 0; j < 8; ++j) s += (float)w[j] * a[j];
  return s;
}

// ---------------- PE table ----------------
__global__ __launch_bounds__(256) void pe_kernel(float* __restrict__ pe) {
  int s = blockIdx.x;
  int d2 = threadIdx.x;
  float div = expf((float)(2 * d2) * PE_C);
  float arg = (float)s * div;
  pe[(size_t)s * DM + 2 * d2] = sinf(arg);
  pe[(size_t)s * DM + 2 * d2 + 1] = cosf(arg);
}

// ---------------- embedding ----------------
__global__ __launch_bounds__(256) void embed_enc(const int* __restrict__ x,
                                                 const float* __restrict__ emb,
                                                 const float* __restrict__ pe,
                                                 float* __restrict__ e,
                                                 __bf16* __restrict__ eb) {
  int idx = blockIdx.x * 256 + threadIdx.x;
  int d = idx & (DM - 1);
  int bs = idx >> 9;
  int s = bs & (SEQ - 1);
  int tok = x[bs];
  float v = emb[(size_t)tok * DM + d] * EMB_SCALE + pe[(size_t)s * DM + d];
  e[idx] = v;
  eb[idx] = (__bf16)v;
}

__global__ __launch_bounds__(256) void embed_dec(const int* __restrict__ t,
                                                 const float* __restrict__ emb,
                                                 float* __restrict__ dd) {
  int idx = blockIdx.x * 256 + threadIdx.x;
  int d = idx & (DM - 1);
  int b = idx >> 9;
  float pe = (d & 1) ? 1.0f : 0.0f;
  dd[idx] = emb[(size_t)t[b] * DM + d] * EMB_SCALE + pe;
}

// ---------------- weight transpose fp32[K][N] -> bf16[N][K] ----------------
__global__ __launch_bounds__(256) void transpose_w(const float* __restrict__ W,
                                                   __bf16* __restrict__ WT,
                                                   int K, int N) {
  __shared__ float t[32][33];
  size_t off = (size_t)blockIdx.z * K * N;
  W += off; WT += off;
  int k0 = blockIdx.y * 32, n0 = blockIdx.x * 32;
  int tx = threadIdx.x & 7, ty = threadIdx.x >> 3;
  float4 v = *(const float4*)&W[(size_t)(k0 + ty) * N + n0 + tx * 4];
  t[ty][tx * 4 + 0] = v.x; t[ty][tx * 4 + 1] = v.y;
  t[ty][tx * 4 + 2] = v.z; t[ty][tx * 4 + 3] = v.w;
  __syncthreads();
  bf16x4 o;
  o[0] = (__bf16)t[tx * 4 + 0][ty];
  o[1] = (__bf16)t[tx * 4 + 1][ty];
  o[2] = (__bf16)t[tx * 4 + 2][ty];
  o[3] = (__bf16)t[tx * 4 + 3][ty];
  *(bf16x4*)&WT[(size_t)(n0 + ty) * K + k0 + tx * 4] = o;
}

// out_w fp32 [512][1000] -> bf16 [1000][512] (guarded tail)
__global__ __launch_bounds__(256) void transpose_ow(const float* __restrict__ W,
                                                    __bf16* __restrict__ WT) {
  __shared__ float t[32][33];
  int n0 = blockIdx.x * 32, k0 = blockIdx.y * 32;
  int tid = threadIdx.x;
  for (int i = tid; i < 1024; i += 256) {
    int kk = i >> 5, nn = i & 31;
    t[kk][nn] = (n0 + nn < OUTD) ? W[(size_t)(k0 + kk) * OUTD + n0 + nn] : 0.f;
  }
  __syncthreads();
  for (int i = tid; i < 1024; i += 256) {
    int nn = i >> 5, kk = i & 31;
    if (n0 + nn < OUTD)
      WT[(size_t)(n0 + nn) * DM + k0 + kk] = (__bf16)t[kk][nn];
  }
}

// ---------------- MFMA GEMM: 256 thr / 4 waves, BM=128 x BN=64 tiles,
// per-wave 64x32 output (acc[4][2]), dbuf staging (T3 2-phase), XCD swizzle.
// LDS 48KB -> 3 blocks/CU (R3 structure: proven best; R4's deep pipeline
// regressed by costing a block/CU).
template <int BN, int SK, bool RELU, bool WF32, bool WBF16, bool TRV, bool KVM>
__global__ __launch_bounds__(256) void mfma_gemm(
    const __bf16* __restrict__ A, const __bf16* __restrict__ BT,
    const float* __restrict__ bias, float* __restrict__ C,
    __bf16* __restrict__ Cb, __bf16* __restrict__ Vt, int M, int N, int K,
    long btStride, long bStride, long cStride) {
  // XCD swizzle: each XCD owns a contiguous y-chunk; x fastest, z slowest.
  int gx = gridDim.x, gy = gridDim.y;
  int lin = blockIdx.x + gx * (blockIdx.y + gy * blockIdx.z);
  int xcd = lin & 7, li = lin >> 3;
  int yc = gy >> 3;
  int bx = li % gx;
  int t2 = li / gx;
  int by = xcd * yc + (t2 % yc);
  int z = t2 / yc;

  if (SK == 1) {
    if (KVM) {
      long idx = (long)(z >> 1) * 3 + 1 + (z & 1);
      BT += idx * btStride;
      bias += idx * bStride;
    } else {
      BT += (size_t)z * btStride;
      bias += (size_t)z * bStride;
    }
  }
  if (WF32) C += (size_t)z * cStride;
  if (WBF16) Cb += (size_t)z * cStride;

  constexpr int NI = BN / 32;
  __shared__ __bf16 As[2][128 * 64];
  __shared__ __bf16 Bs[2][BN * 64];

  int tid = threadIdx.x;
  int wave = tid >> 6, lane = tid & 63;
  int wm = wave >> 1, wn = wave & 1;           // 2 x 2 wave grid
  int quad = lane >> 4, l16 = lane & 15;
  int rlane = lane >> 3, c8 = lane & 7;
  int m0 = by * 128, n0 = bx * BN;
  int gcol = ((c8 ^ rlane) * 8);

  f32x4 acc[4][NI];
#pragma unroll
  for (int i = 0; i < 4; ++i)
#pragma unroll
    for (int j = 0; j < NI; ++j) acc[i][j] = (f32x4){0.f, 0.f, 0.f, 0.f};

  auto stage = [&](int buf, int k0) {
#pragma unroll
    for (int j = 0; j < 4; ++j) {
      int rb = j * 32 + wave * 8;
      load16_lds(&A[(size_t)(m0 + rb + rlane) * K + k0 + gcol],
                 &As[buf][rb * 64]);
    }
#pragma unroll
    for (int j = 0; j < BN / 32; ++j) {
      int rb = j * 32 + wave * 8;
      load16_lds(&BT[(size_t)(n0 + rb + rlane) * K + k0 + gcol],
                 &Bs[buf][rb * 64]);
    }
  };

  int kLen = (SK > 1) ? (K / SK) : K;
  int kBeg = (SK > 1) ? z * kLen : 0;
  const int NT = kLen >> 6;
  stage(0, kBeg);
  __syncthreads();
  for (int t = 0; t < NT; ++t) {
    int cur = t & 1;
    if (t + 1 < NT) stage(cur ^ 1, kBeg + ((t + 1) << 6));
#pragma unroll
    for (int kk = 0; kk < 64; kk += 32) {
      bf16x8 af[4], bfr[NI];
#pragma unroll
      for (int i = 0; i < 4; ++i) {
        int row = wm * 64 + i * 16 + l16;
        af[i] = *(const bf16x8*)&As[cur][row * 64 + ((((kk >> 3) + quad) ^ (row & 7)) * 8)];
      }
#pragma unroll
      for (int i = 0; i < NI; ++i) {
        int row = wn * (BN / 2) + i * 16 + l16;
        bfr[i] = *(const bf16x8*)&Bs[cur][row * 64 + ((((kk >> 3) + quad) ^ (row & 7)) * 8)];
      }
#pragma unroll
      for (int mi = 0; mi < 4; ++mi)
#pragma unroll
        for (int ni = 0; ni < NI; ++ni)
          acc[mi][ni] = __builtin_amdgcn_mfma_f32_16x16x32_bf16(
              af[mi], bfr[ni], acc[mi][ni], 0, 0, 0);
    }
    __syncthreads();
  }

#pragma unroll
  for (int ni = 0; ni < NI; ++ni) {
    int col = n0 + wn * (BN / 2) + ni * 16 + l16;
    float bv = (SK == 1 || z == 0) ? bias[col] : 0.f;
    if (TRV && z == 2) {
      int b = m0 >> 9;
#pragma unroll
      for (int mi = 0; mi < 4; ++mi) {
        int srow = (m0 & 511) + wm * 64 + mi * 16 + quad * 4;
        bf16x4 pk;
#pragma unroll
        for (int r = 0; r < 4; ++r) pk[r] = (__bf16)(acc[mi][ni][r] + bv);
        *(bf16x4*)&Vt[((size_t)(b * 512 + col)) * 512 + srow] = pk;
      }
    } else {
#pragma unroll
      for (int mi = 0; mi < 4; ++mi) {
#pragma unroll
        for (int r = 0; r < 4; ++r) {
          int row = m0 + wm * 64 + mi * 16 + quad * 4 + r;
          float v = acc[mi][ni][r] + bv;
          if (RELU) v = fmaxf(v, 0.f);
          if (WF32) C[(size_t)row * N + col] = v;
          if (WBF16) Cb[(size_t)row * N + col] = (__bf16)v;
        }
      }
    }
  }
}

// ---------------- MFMA encoder attention: 32 q-rows/block --------------
// Each staged K/V tile now feeds 2x the q-rows: 4 MFMA per wave per phase
// (was 2), half the machine-wide phase count. LDS 48.5KB -> 3 blocks/CU.
#define SCP 520
__global__ __launch_bounds__(256) void attn_mfma(const __bf16* __restrict__ QKV,
                                                 const __bf16* __restrict__ Vt,
                                                 float* __restrict__ O) {
  __shared__ __bf16 Sc[32 * SCP];
  __shared__ __bf16 Tt[2][64 * 64];

  const long ACTL = (long)NB * SEQ * DM;
  int tid = threadIdx.x;
  int wave = tid >> 6, lane = tid & 63;
  int quad = lane >> 4, l16 = lane & 15;
  int rlane = lane >> 3, c8 = lane & 7;
  int qs = wave & 1;        // q-sub (16 rows each)
  int half = wave >> 1;     // key-col half (QK) / d-col half (PV)
  // XCD swizzle: chunk by bh so each XCD's L2 holds few K/V panels.
  int lin = blockIdx.x + gridDim.x * blockIdx.y;
  int xcd = lin & 7, li = lin >> 3;
  int yc = gridDim.y >> 3;
  int q0 = (li % gridDim.x) * 32;
  int bh = xcd * yc + li / gridDim.x;
  int b = bh >> 3, h = bh & 7;
  const __bf16* Q = QKV;
  const __bf16* Kp = QKV + ACTL;
  size_t baseQ = ((size_t)b * SEQ + q0 + qs * 16) * DM + h * DK;
  size_t baseK = ((size_t)b * SEQ) * DM + h * DK;
  const __bf16* VtB = Vt + ((size_t)(b * 512 + h * 64)) * 512;
  int gcol = (c8 ^ rlane) * 8;

  bf16x8 af0 = *(const bf16x8*)&Q[baseQ + (size_t)l16 * DM + quad * 8];
  bf16x8 af1 = *(const bf16x8*)&Q[baseQ + (size_t)l16 * DM + 32 + quad * 8];

  auto stageK = [&](int buf, int kt) {
#pragma unroll
    for (int j = 0; j < 2; ++j) {
      int row = j * 32 + wave * 8 + rlane;
      load16_lds(&Kp[baseK + (size_t)(kt * 64 + row) * DM + gcol],
                 &Tt[buf][(j * 32 + wave * 8) * 64]);
    }
  };
  auto stageV = [&](int buf, int kt) {
#pragma unroll
    for (int j = 0; j < 2; ++j) {
      int row = j * 32 + wave * 8 + rlane;
      load16_lds(&VtB[(size_t)row * 512 + kt * 64 + gcol],
                 &Tt[buf][(j * 32 + wave * 8) * 64]);
    }
  };

  // ---- QK^T, 8 tiles of 64 keys, prefetch-1 ----
  stageK(0, 0);
  __syncthreads();
  for (int kt = 0; kt < 8; ++kt) {
    int cur = kt & 1;
    if (kt < 7) stageK(cur ^ 1, kt + 1);
    f32x4 a0 = (f32x4){0.f, 0.f, 0.f, 0.f};
    f32x4 a1 = (f32x4){0.f, 0.f, 0.f, 0.f};
    int kr0 = half * 32 + l16, sw0 = kr0 & 7;
    int kr1 = kr0 + 16, sw1 = kr1 & 7;
    bf16x8 b00 = *(const bf16x8*)&Tt[cur][kr0 * 64 + ((quad ^ sw0) * 8)];
    bf16x8 b01 = *(const bf16x8*)&Tt[cur][kr0 * 64 + (((4 + quad) ^ sw0) * 8)];
    bf16x8 b10 = *(const bf16x8*)&Tt[cur][kr1 * 64 + ((quad ^ sw1) * 8)];
    bf16x8 b11 = *(const bf16x8*)&Tt[cur][kr1 * 64 + (((4 + quad) ^ sw1) * 8)];
    a0 = __builtin_amdgcn_mfma_f32_16x16x32_bf16(af0, b00, a0, 0, 0, 0);
    a0 = __builtin_amdgcn_mfma_f32_16x16x32_bf16(af1, b01, a0, 0, 0, 0);
    a1 = __builtin_amdgcn_mfma_f32_16x16x32_bf16(af0, b10, a1, 0, 0, 0);
    a1 = __builtin_amdgcn_mfma_f32_16x16x32_bf16(af1, b11, a1, 0, 0, 0);
#pragma unroll
    for (int r = 0; r < 4; ++r) {
      int srow = qs * 16 + quad * 4 + r;
      Sc[srow * SCP + kt * 64 + half * 32 + l16] = (__bf16)(a0[r] * 0.125f);
      Sc[srow * SCP + kt * 64 + half * 32 + 16 + l16] = (__bf16)(a1[r] * 0.125f);
    }
    __syncthreads();
  }

  // prefetch first V tile under softmax
  stageV(0, 0);

  // ---- softmax over 32 rows (8 per wave) ----
#pragma unroll
  for (int rr = 0; rr < 8; ++rr) {
    int r = wave * 8 + rr;
    float v[8];
    float mx = -1e30f;
#pragma unroll
    for (int j = 0; j < 8; ++j) {
      v[j] = (float)Sc[r * SCP + j * 64 + lane];
      mx = fmaxf(mx, v[j]);
    }
    for (int o = 32; o > 0; o >>= 1) mx = fmaxf(mx, __shfl_xor(mx, o));
    float sum = 0.f;
#pragma unroll
    for (int j = 0; j < 8; ++j) { v[j] = __expf(v[j] - mx); sum += v[j]; }
    for (int o = 32; o > 0; o >>= 1) sum += __shfl_xor(sum, o);
    float inv = 1.f / sum;
#pragma unroll
    for (int j = 0; j < 8; ++j)
      Sc[r * SCP + j * 64 + lane] = (__bf16)(v[j] * inv);
  }
  __syncthreads();  // softmax Sc visible + V tile 0 staged (vmcnt drain)

  // ---- PV, 8 tiles, prefetch-1; wave: qs rows x (half*32) d-cols ----
  f32x4 o0 = (f32x4){0.f, 0.f, 0.f, 0.f};
  f32x4 o1 = (f32x4){0.f, 0.f, 0.f, 0.f};
  int dr0 = half * 32 + l16, sd0 = dr0 & 7;
  int dr1 = dr0 + 16, sd1 = dr1 & 7;
  for (int kt = 0; kt < 8; ++kt) {
    int cur = kt & 1;
    if (kt < 7) stageV(cur ^ 1, kt + 1);
#pragma unroll
    for (int kk = 0; kk < 64; kk += 32) {
      bf16x8 pa = *(const bf16x8*)&Sc[(qs * 16 + l16) * SCP + kt * 64 + kk + quad * 8];
      bf16x8 v0 = *(const bf16x8*)&Tt[cur][dr0 * 64 + ((((kk >> 3) + quad) ^ sd0) * 8)];
      bf16x8 v1 = *(const bf16x8*)&Tt[cur][dr1 * 64 + ((((kk >> 3) + quad) ^ sd1) * 8)];
      o0 = __builtin_amdgcn_mfma_f32_16x16x32_bf16(pa, v0, o0, 0, 0, 0);
      o1 = __builtin_amdgcn_mfma_f32_16x16x32_bf16(pa, v1, o1, 0, 0, 0);
    }
    __syncthreads();
  }
#pragma unroll
  for (int r = 0; r < 4; ++r) {
    size_t rowOff = ((size_t)b * SEQ + q0 + qs * 16 + quad * 4 + r) * DM + h * DK;
    O[rowOff + half * 32 + l16] = o0[r];
    O[rowOff + half * 32 + 16 + l16] = o1[r];
  }
}

// ---------------- residual + layernorm (optional second summand x2) -------
template <bool WB>
__global__ __launch_bounds__(256) void add_ln(
    const float* __restrict__ x, const float* __restrict__ x2,
    const float* __restrict__ res, const float* __restrict__ cbias,
    const float* __restrict__ g, const float* __restrict__ beta,
    float* __restrict__ y, __bf16* __restrict__ yb) {
  int row = blockIdx.x;
  int tid = threadIdx.x;
  const float* xr = x + (size_t)row * DM;
  const float* rr = res + (size_t)row * DM;
  float b0 = cbias ? cbias[tid] : 0.f;
  float b1 = cbias ? cbias[tid + 256] : 0.f;
  float v0 = xr[tid] + b0 + rr[tid];
  float v1 = xr[tid + 256] + b1 + rr[tid + 256];
  if (x2) {
    const float* x2r = x2 + (size_t)row * DM;
    v0 += x2r[tid];
    v1 += x2r[tid + 256];
  }
  float s = v0 + v1, sq = v0 * v0 + v1 * v1;
  for (int o = 32; o > 0; o >>= 1) {
    s += __shfl_xor(s, o);
    sq += __shfl_xor(sq, o);
  }
  __shared__ float ps[4], pq[4];
  int wv = tid >> 6;
  if ((tid & 63) == 0) { ps[wv] = s; pq[wv] = sq; }
  __syncthreads();
  s = ps[0] + ps[1] + ps[2] + ps[3];
  sq = pq[0] + pq[1] + pq[2] + pq[3];
  float mean = s * (1.f / DM);
  float var = sq * (1.f / DM) - mean * mean;
  float rstd = rsqrtf(var + 1e-5f);
  float o0 = (v0 - mean) * rstd * g[tid] + beta[tid];
  float o1 = (v1 - mean) * rstd * g[tid + 256] + beta[tid + 256];
  y[(size_t)row * DM + tid] = o0;
  y[(size_t)row * DM + tid + 256] = o1;
  if (WB) {
    yb[(size_t)row * DM + tid] = (__bf16)o0;
    yb[(size_t)row * DM + tid + 256] = (__bf16)o1;
  }
}

// ============ fused decoder kernels (M = 8 rows) ============

// dd[r] = LN(dd[r] + dd[r] @ WvT^T + bv)  -- one block per row
__global__ __launch_bounds__(256) void dec_vln(
    float* __restrict__ dd, const __bf16* __restrict__ WvT,
    const float* __restrict__ bv, const float* __restrict__ g,
    const float* __restrict__ beta) {
  __shared__ float arow[DM];
  int r = blockIdx.x, tid = threadIdx.x;
  arow[tid] = dd[(size_t)r * DM + tid];
  arow[tid + 256] = dd[(size_t)r * DM + tid + 256];
  __syncthreads();
  float out[2];
#pragma unroll
  for (int cc = 0; cc < 2; ++cc) {
    int c = tid + cc * 256;
    const __bf16* w = &WvT[(size_t)c * DM];
    float acc = 0.f;
#pragma unroll 4
    for (int k = 0; k < DM; k += 8) acc += dot8(*(const bf16x8*)&w[k], &arow[k]);
    out[cc] = arow[c] + acc + bv[c];
  }
  float s = out[0] + out[1], sq = out[0] * out[0] + out[1] * out[1];
  for (int o = 32; o > 0; o >>= 1) { s += __shfl_xor(s, o); sq += __shfl_xor(sq, o); }
  __shared__ float ps[4], pq[4];
  int wv = tid >> 6;
  if ((tid & 63) == 0) { ps[wv] = s; pq[wv] = sq; }
  __syncthreads();
  s = ps[0] + ps[1] + ps[2] + ps[3];
  sq = pq[0] + pq[1] + pq[2] + pq[3];
  float mean = s * (1.f / DM);
  float rstd = rsqrtf(sq * (1.f / DM) - mean * mean + 1e-5f);
  dd[(size_t)r * DM + tid] = (out[0] - mean) * rstd * g[tid] + beta[tid];
  dd[(size_t)r * DM + tid + 256] = (out[1] - mean) * rstd * g[tid + 256] + beta[tid + 256];
}

// q = dd[b] @ Wq[:,h*64..] + bq; attention over 512 bf16 keys/values -> da
// one block per (b,h)
__global__ __launch_bounds__(256) void dec_qattn(
    const float* __restrict__ dd, const __bf16* __restrict__ WqT,
    const float* __restrict__ qb, const __bf16* __restrict__ Kb,
    const __bf16* __restrict__ Vb, float* __restrict__ da) {
  __shared__ float arow[DM];
  __shared__ float red[4][64];
  __shared__ float q[64];
  __shared__ float sc[SEQ];
  __shared__ float wred[4];

  int bh = blockIdx.x, b = bh >> 3, h = bh & 7;
  int tid = threadIdx.x, lane = tid & 63, wave = tid >> 6;
  arow[tid] = dd[(size_t)b * DM + tid];
  arow[tid + 256] = dd[(size_t)b * DM + tid + 256];
  __syncthreads();

  // q-gemv: 64 cols x 4 k-subs
  {
    int c = tid & 63, s = tid >> 6;
    const __bf16* w = &WqT[(size_t)(h * 64 + c) * DM + s * 128];
    float acc = 0.f;
#pragma unroll
    for (int k = 0; k < 128; k += 8) acc += dot8(*(const bf16x8*)&w[k], &arow[s * 128 + k]);
    red[s][c] = acc;
  }
  __syncthreads();
  if (tid < 64) q[tid] = red[0][tid] + red[1][tid] + red[2][tid] + red[3][tid] + qb[h * 64 + tid];
  __syncthreads();

  // scores
  for (int key = tid; key < SEQ; key += 256) {
    const __bf16* kp = &Kb[((size_t)b * SEQ + key) * DM + h * 64];
    float acc = 0.f;
#pragma unroll
    for (int k = 0; k < 64; k += 8) acc += dot8(*(const bf16x8*)&kp[k], &q[k]);
    sc[key] = acc * 0.125f;
  }
  __syncthreads();
  float m = -1e30f;
  for (int j = tid; j < SEQ; j += 256) m = fmaxf(m, sc[j]);
  for (int o = 32; o > 0; o >>= 1) m = fmaxf(m, __shfl_xor(m, o));
  if (lane == 0) wred[wave] = m;
  __syncthreads();
  m = fmaxf(fmaxf(wred[0], wred[1]), fmaxf(wred[2], wred[3]));
  float sum = 0.f;
  for (int j = tid; j < SEQ; j += 256) {
    float p = __expf(sc[j] - m);
    sc[j] = p;
    sum += p;
  }
  for (int o = 32; o > 0; o >>= 1) sum += __shfl_xor(sum, o);
  __syncthreads();   // sc writes done before reuse of wred
  if (lane == 0) wred[wave] = sum;
  __syncthreads();
  float inv = 1.f / (wred[0] + wred[1] + wred[2] + wred[3]);

  // PV
  {
    int d = tid & 63, s = tid >> 6;
    float acc = 0.f;
    const __bf16* vp = &Vb[((size_t)b * SEQ + s * 128) * DM + h * 64 + d];
#pragma unroll 8
    for (int k = 0; k < 128; ++k) acc += sc[s * 128 + k] * (float)vp[(size_t)k * DM];
    red[s][d] = acc;
  }
  __syncthreads();
  if (tid < 64)
    da[(size_t)b * DM + h * 64 + tid] =
        (red[0][tid] + red[1][tid] + red[2][tid] + red[3][tid]) * inv;
}

// h[r][col] = relu(dd[r] @ W1T[col] + b1[col]); wave per col, 4 cols/block
__global__ __launch_bounds__(256) void dec_ffn1(
    const float* __restrict__ dd, const __bf16* __restrict__ W1T,
    const float* __restrict__ b1, float* __restrict__ h) {
  __shared__ float a[8][DM];
  int tid = threadIdx.x, lane = tid & 63, wave = tid >> 6;
  for (int i = tid; i < 8 * DM; i += 256) a[i >> 9][i & 511] = dd[i];
  __syncthreads();
  int col = blockIdx.x * 4 + wave;
  bf16x8 w = *(const bf16x8*)&W1T[(size_t)col * DM + lane * 8];
  float acc[8];
#pragma unroll
  for (int r = 0; r < 8; ++r) acc[r] = dot8(w, &a[r][lane * 8]);
#pragma unroll
  for (int r = 0; r < 8; ++r)
    for (int o = 32; o > 0; o >>= 1) acc[r] += __shfl_xor(acc[r], o);
  if (lane == 0) {
    float bb = b1[col];
#pragma unroll
    for (int r = 0; r < 8; ++r) h[(size_t)r * DFF + col] = fmaxf(acc[r] + bb, 0.f);
  }
}

// df[r][col] = h[r] @ W2T[col] + b2[col]; 2 cols/block, 2 waves per col
__global__ __launch_bounds__(256) void dec_ffn2(
    const float* __restrict__ h, const __bf16* __restrict__ W2T,
    const float* __restrict__ b2, float* __restrict__ df) {
  __shared__ float red[4][8];
  int tid = threadIdx.x, lane = tid & 63, wave = tid >> 6;
  int c = wave >> 1, half = wave & 1;
  int col = blockIdx.x * 2 + c;
  int k0 = half * 1024 + lane * 8;
  bf16x8 w0 = *(const bf16x8*)&W2T[(size_t)col * DFF + k0];
  bf16x8 w1 = *(const bf16x8*)&W2T[(size_t)col * DFF + k0 + 512];
  float acc[8];
#pragma unroll
  for (int r = 0; r < 8; ++r) {
    float4 h0a = *(const float4*)&h[(size_t)r * DFF + k0];
    float4 h0b = *(const float4*)&h[(size_t)r * DFF + k0 + 4];
    float4 h1a = *(const float4*)&h[(size_t)r * DFF + k0 + 512];
    float4 h1b = *(const float4*)&h[(size_t)r * DFF + k0 + 516];
    float hh0[8] = {h0a.x, h0a.y, h0a.z, h0a.w, h0b.x, h0b.y, h0b.z, h0b.w};
    float hh1[8] = {h1a.x, h1a.y, h1a.z, h1a.w, h1b.x, h1b.y, h1b.z, h1b.w};
    acc[r] = dot8(w0, hh0) + dot8(w1, hh1);
  }
#pragma unroll
  for (int r = 0; r < 8; ++r)
    for (int o = 32; o > 0; o >>= 1) acc[r] += __shfl_xor(acc[r], o);
  if (lane == 0) {
#pragma unroll
    for (int r = 0; r < 8; ++r) red[wave][r] = acc[r];
  }
  __syncthreads();
  if (tid < 16) {
    int cc = tid >> 3, r = tid & 7;
    int ocol = blockIdx.x * 2 + cc;
    df[(size_t)r * DM + ocol] =
        red[cc * 2][r] + red[cc * 2 + 1][r] + b2[ocol];
  }
}

// out[r][col] = dd[r] @ WoT[col] + ob[col]; wave per col, 4 cols/block
__global__ __launch_bounds__(256) void dec_out(
    const float* __restrict__ dd, const __bf16* __restrict__ WoT,
    const float* __restrict__ ob, float* __restrict__ out) {
  __shared__ float a[8][DM];
  int tid = threadIdx.x, lane = tid & 63, wave = tid >> 6;
  for (int i = tid; i < 8 * DM; i += 256) a[i >> 9][i & 511] = dd[i];
  __syncthreads();
  int col = blockIdx.x * 4 + wave;
  bf16x8 w = *(const bf16x8*)&WoT[(size_t)col * DM + lane * 8];
  float acc[8];
#pragma unroll
  for (int r = 0; r < 8; ++r) acc[r] = dot8(w, &a[r][lane * 8]);
#pragma unroll
  for (int r = 0; r < 8; ++r)
    for (int o = 32; o > 0; o >>= 1) acc[r] += __shfl_xor(acc[r], o);
  if (lane == 0) {
    float bb = ob[col];
#pragma unroll
    for (int r = 0; r < 8; ++r) out[(size_t)r * OUTD + col] = acc[r] + bb;
  }
}

// ---------------------------------------------------------------------------
extern "C" void kernel_launch(void* const* d_in, const int* in_sizes, int n_in,
                              void* d_out, int out_size, void* d_ws, size_t ws_size,
                              hipStream_t stream) {
  const int* x = (const int*)d_in[0];
  const int* target = (const int*)d_in[1];
  const float* in_emb = (const float*)d_in[2];
  const float* out_emb = (const float*)d_in[3];
  const float* enc_qkv_w = (const float*)d_in[4];
  const float* enc_qkv_b = (const float*)d_in[5];
  const float* enc_ln1_g = (const float*)d_in[6];
  const float* enc_ln1_b = (const float*)d_in[7];
  const float* enc_ffn1_w = (const float*)d_in[8];
  const float* enc_ffn1_b = (const float*)d_in[9];
  const float* enc_ffn2_w = (const float*)d_in[10];
  const float* enc_ffn2_b = (const float*)d_in[11];
  const float* enc_ln2_g = (const float*)d_in[12];
  const float* enc_ln2_b = (const float*)d_in[13];
  const float* dec_qkv1_w = (const float*)d_in[14];
  const float* dec_qkv1_b = (const float*)d_in[15];
  const float* dec_ln1_g = (const float*)d_in[16];
  const float* dec_ln1_b = (const float*)d_in[17];
  const float* dec_qkv2_w = (const float*)d_in[18];
  const float* dec_qkv2_b = (const float*)d_in[19];
  const float* dec_ln2_g = (const float*)d_in[20];
  const float* dec_ln2_b = (const float*)d_in[21];
  const float* dec_ffn1_w = (const float*)d_in[22];
  const float* dec_ffn1_b = (const float*)d_in[23];
  const float* dec_ffn2_w = (const float*)d_in[24];
  const float* dec_ffn2_b = (const float*)d_in[25];
  const float* dec_ln3_g = (const float*)d_in[26];
  const float* dec_ln3_b = (const float*)d_in[27];
  const float* out_w = (const float*)d_in[28];
  const float* out_b = (const float*)d_in[29];

  const long ACTL = (long)NB * SEQ * DM;           // 2M elems
  const int M = NB * SEQ;                           // 4096
  const long WQS = (long)DM * DM;
  const long WFS = (long)DM * DFF;

  char* p = (char*)d_ws;
  float* e = (float*)p;            p += ACTL * 4;
  float* tb = (float*)p;           p += ACTL * 4;
  float* pe = (float*)p;           p += (long)SEQ * DM * 4;
  float* dd = (float*)p;           p += NB * DM * 4;
  float* da = (float*)p;           p += NB * DM * 4;
  float* dh = (float*)p;           p += NB * DFF * 4;
  float* df = (float*)p;           p += NB * DM * 4;
  p = (char*)(((uintptr_t)p + 255) & ~(uintptr_t)255);
  __bf16* eb = (__bf16*)p;         p += ACTL * 2;
  __bf16* qkvb = (__bf16*)p;       p += 3 * ACTL * 2;   // Q,K; slice 2 = V^T
  __bf16* hbb = (__bf16*)p;        p += (long)M * DFF * 2;
  __bf16* kvb = (__bf16*)p;        p += 12L * ACTL * 2; // [layer][K,V][4096][512]
  __bf16* wtq = (__bf16*)p;        p += 18L * WQS * 2;
  __bf16* wtf1 = (__bf16*)p;       p += 6L * WFS * 2;
  __bf16* wtf2 = (__bf16*)p;       p += 6L * WFS * 2;
  __bf16* wtd = (__bf16*)p;        p += 18L * WQS * 2;  // dec_qkv2^T
  __bf16* wtd1 = (__bf16*)p;       p += 18L * WQS * 2;  // dec_qkv1^T
  __bf16* wf1t = (__bf16*)p;       p += 6L * WFS * 2;
  __bf16* wf2t = (__bf16*)p;       p += 6L * WFS * 2;
  __bf16* wot = (__bf16*)p;        p += (long)OUTD * DM * 2;

  __bf16* vtb = qkvb + 2 * ACTL;
  // split-K partial-1 for encoder FFN2: reuse kvb region (idle until the
  // KV gemm after the encoder loop)
  float* tb2 = (float*)kvb;
  long tb2Off = (long)(tb2 - tb);  // element stride from partial0 to partial1

  // ---- one-time prep ----
  pe_kernel<<<SEQ, 256, 0, stream>>>(pe);
  transpose_w<<<dim3(16, 16, 18), 256, 0, stream>>>(enc_qkv_w, wtq, DM, DM);
  transpose_w<<<dim3(64, 16, 6), 256, 0, stream>>>(enc_ffn1_w, wtf1, DM, DFF);
  transpose_w<<<dim3(16, 64, 6), 256, 0, stream>>>(enc_ffn2_w, wtf2, DFF, DM);
  transpose_w<<<dim3(16, 16, 18), 256, 0, stream>>>(dec_qkv2_w, wtd, DM, DM);
  transpose_w<<<dim3(16, 16, 18), 256, 0, stream>>>(dec_qkv1_w, wtd1, DM, DM);
  transpose_w<<<dim3(64, 16, 6), 256, 0, stream>>>(dec_ffn1_w, wf1t, DM, DFF);
  transpose_w<<<dim3(16, 64, 6), 256, 0, stream>>>(dec_ffn2_w, wf2t, DFF, DM);
  transpose_ow<<<dim3(32, 16), 256, 0, stream>>>(out_w, wot);

  // ---- encoder ----
  embed_enc<<<(M * DM) / 256, 256, 0, stream>>>(x, in_emb, pe, e, eb);
  for (int i = 0; i < NL; ++i) {
    mfma_gemm<64, 1, false, false, true, true, false><<<dim3(8, 32, 3), 256, 0, stream>>>(
        eb, wtq + (size_t)i * 3 * WQS, enc_qkv_b + (size_t)i * 3 * DM,
        nullptr, qkvb, vtb, M, DM, DM, WQS, DM, ACTL);
    attn_mfma<<<dim3(SEQ / 32, NB * NH), 256, 0, stream>>>(qkvb, vtb, tb);
    add_ln<true><<<M, 256, 0, stream>>>(tb, nullptr, e, nullptr,
                                        enc_ln1_g + i * DM, enc_ln1_b + i * DM,
                                        e, eb);
    mfma_gemm<64, 1, true, false, true, false, false><<<dim3(32, 32, 1), 256, 0, stream>>>(
        eb, wtf1 + (size_t)i * WFS, enc_ffn1_b + (size_t)i * DFF,
        nullptr, hbb, nullptr, M, DFF, DM, 0, 0, 0);
    mfma_gemm<64, 2, false, true, false, false, false><<<dim3(8, 32, 2), 256, 0, stream>>>(
        hbb, wtf2 + (size_t)i * WFS, enc_ffn2_b + (size_t)i * DM,
        tb, nullptr, nullptr, M, DM, DFF, 0, 0, tb2Off);
    add_ln<true><<<M, 256, 0, stream>>>(tb, tb2, e, nullptr,
                                        enc_ln2_g + i * DM, enc_ln2_b + i * DM,
                                        e, eb);
  }

  // ---- cross K/V for all 6 layers in one dispatch (bf16 out) ----
  mfma_gemm<64, 1, false, false, true, false, true><<<dim3(8, 32, 12), 256, 0, stream>>>(
      eb, wtd, dec_qkv2_b, nullptr, kvb, nullptr, M, DM, DM, WQS, DM, ACTL);

  // ---- decoder (seq len 1, fully fused, no atomics/memsets) ----
  embed_dec<<<(NB * DM) / 256, 256, 0, stream>>>(target, out_emb, dd);
  for (int i = 0; i < NL; ++i) {
    dec_vln<<<8, 256, 0, stream>>>(
        dd, wtd1 + ((size_t)i * 3 + 2) * WQS, dec_qkv1_b + ((size_t)i * 3 + 2) * DM,
        dec_ln1_g + i * DM, dec_ln1_b + i * DM);
    dec_qattn<<<64, 256, 0, stream>>>(
        dd, wtd + (size_t)i * 3 * WQS, dec_qkv2_b + (size_t)i * 3 * DM,
        kvb + (size_t)i * 2 * ACTL, kvb + ((size_t)i * 2 + 1) * ACTL, da);
    add_ln<false><<<NB, 256, 0, stream>>>(
        da, nullptr, dd, nullptr, dec_ln2_g + i * DM, dec_ln2_b + i * DM,
        dd, nullptr);
    dec_ffn1<<<DFF / 4, 256, 0, stream>>>(
        dd, wf1t + (size_t)i * WFS, dec_ffn1_b + (size_t)i * DFF, dh);
    dec_ffn2<<<DM / 2, 256, 0, stream>>>(
        dh, wf2t + (size_t)i * WFS, dec_ffn2_b + (size_t)i * DM, df);
    add_ln<false><<<NB, 256, 0, stream>>>(
        df, nullptr, dd, nullptr, dec_ln3_g + i * DM, dec_ln3_b + i * DM,
        dd, nullptr);
  }

  // ---- output projection (direct, bias fused) ----
  dec_out<<<OUTD / 4, 256, 0, stream>>>(dd, wot, out_b, (float*)d_out);
}

// Round 6
// 1126.715 us; speedup vs baseline: 1.0774x; 1.0370x over previous
//
#include <hip/hip_runtime.h>
#include <hip/hip_bf16.h>

#define DM 512
#define NH 8
#define DK 64
#define SEQ 512
#define NB 8
#define NL 6
#define DFF 2048
#define OUTD 1000
#define EMB_SCALE 22.627416997969522f
#define PE_C (-0.017988946039015984f)   // -ln(10000)/512

typedef __bf16 bf16x8 __attribute__((ext_vector_type(8)));
typedef __bf16 bf16x4 __attribute__((ext_vector_type(4)));
typedef float f32x4 __attribute__((ext_vector_type(4)));

__device__ __forceinline__ void load16_lds(const __bf16* g, __bf16* l) {
  __builtin_amdgcn_global_load_lds(
      (const __attribute__((address_space(1))) void*)g,
      (__attribute__((address_space(3))) void*)l, 16, 0, 0);
}

__device__ __forceinline__ float dot8(bf16x8 w, const float* a) {
  float s = 0.f;
#pragma unroll
  for (int j = 0; j < 8; ++j) s += (float)w[j] * a[j];
  return s;
}

// block-wide LN over a 512-elem row held as (v0 @ tid, v1 @ tid+256).
// writes normalized row into out[0..511]; trailing sync makes it visible.
__device__ __forceinline__ void ln_pair(float v0, float v1, int tid,
                                        const float* __restrict__ g,
                                        const float* __restrict__ beta,
                                        float* out, float* ps, float* pq) {
  float s = v0 + v1, sq = v0 * v0 + v1 * v1;
  for (int o = 32; o > 0; o >>= 1) { s += __shfl_xor(s, o); sq += __shfl_xor(sq, o); }
  int wv = tid >> 6;
  if ((tid & 63) == 0) { ps[wv] = s; pq[wv] = sq; }
  __syncthreads();
  s = ps[0] + ps[1] + ps[2] + ps[3];
  sq = pq[0] + pq[1] + pq[2] + pq[3];
  float mean = s * (1.f / DM);
  float rstd = rsqrtf(sq * (1.f / DM) - mean * mean + 1e-5f);
  out[tid] = (v0 - mean) * rstd * g[tid] + beta[tid];
  out[tid + 256] = (v1 - mean) * rstd * g[tid + 256] + beta[tid + 256];
  __syncthreads();
}

// ---------------- PE table ----------------
__global__ __launch_bounds__(256) void pe_kernel(float* __restrict__ pe) {
  int s = blockIdx.x;
  int d2 = threadIdx.x;
  float div = expf((float)(2 * d2) * PE_C);
  float arg = (float)s * div;
  pe[(size_t)s * DM + 2 * d2] = sinf(arg);
  pe[(size_t)s * DM + 2 * d2 + 1] = cosf(arg);
}

// ---------------- embedding ----------------
__global__ __launch_bounds__(256) void embed_enc(const int* __restrict__ x,
                                                 const float* __restrict__ emb,
                                                 const float* __restrict__ pe,
                                                 float* __restrict__ e,
                                                 __bf16* __restrict__ eb) {
  int idx = blockIdx.x * 256 + threadIdx.x;
  int d = idx & (DM - 1);
  int bs = idx >> 9;
  int s = bs & (SEQ - 1);
  int tok = x[bs];
  float v = emb[(size_t)tok * DM + d] * EMB_SCALE + pe[(size_t)s * DM + d];
  e[idx] = v;
  eb[idx] = (__bf16)v;
}

// ---------------- weight transpose fp32[K][N] -> bf16[N][K] ----------------
// input slice z*zmul+zadd, output slice z (lets us transpose only used slices)
__global__ __launch_bounds__(256) void transpose_w(const float* __restrict__ W,
                                                   __bf16* __restrict__ WT,
                                                   int K, int N, long zmul,
                                                   long zadd) {
  __shared__ float t[32][33];
  W += (size_t)(blockIdx.z * zmul + zadd) * K * N;
  WT += (size_t)blockIdx.z * K * N;
  int k0 = blockIdx.y * 32, n0 = blockIdx.x * 32;
  int tx = threadIdx.x & 7, ty = threadIdx.x >> 3;
  float4 v = *(const float4*)&W[(size_t)(k0 + ty) * N + n0 + tx * 4];
  t[ty][tx * 4 + 0] = v.x; t[ty][tx * 4 + 1] = v.y;
  t[ty][tx * 4 + 2] = v.z; t[ty][tx * 4 + 3] = v.w;
  __syncthreads();
  bf16x4 o;
  o[0] = (__bf16)t[tx * 4 + 0][ty];
  o[1] = (__bf16)t[tx * 4 + 1][ty];
  o[2] = (__bf16)t[tx * 4 + 2][ty];
  o[3] = (__bf16)t[tx * 4 + 3][ty];
  *(bf16x4*)&WT[(size_t)(n0 + ty) * K + k0 + tx * 4] = o;
}

// out_w fp32 [512][1000] -> bf16 [1000][512] (guarded tail)
__global__ __launch_bounds__(256) void transpose_ow(const float* __restrict__ W,
                                                    __bf16* __restrict__ WT) {
  __shared__ float t[32][33];
  int n0 = blockIdx.x * 32, k0 = blockIdx.y * 32;
  int tid = threadIdx.x;
  for (int i = tid; i < 1024; i += 256) {
    int kk = i >> 5, nn = i & 31;
    t[kk][nn] = (n0 + nn < OUTD) ? W[(size_t)(k0 + kk) * OUTD + n0 + nn] : 0.f;
  }
  __syncthreads();
  for (int i = tid; i < 1024; i += 256) {
    int nn = i >> 5, kk = i & 31;
    if (n0 + nn < OUTD)
      WT[(size_t)(n0 + nn) * DM + k0 + kk] = (__bf16)t[kk][nn];
  }
}

// ---------------- MFMA GEMM: 256 thr / 4 waves, BM=128 x BN=64 tiles,
// per-wave 64x32 output (acc[4][2]), dbuf staging (T3 2-phase), XCD swizzle.
// LDS 48KB -> 3 blocks/CU (R3 structure: proven best).
template <int BN, int SK, bool RELU, bool WF32, bool WBF16, bool TRV, bool KVM>
__global__ __launch_bounds__(256) void mfma_gemm(
    const __bf16* __restrict__ A, const __bf16* __restrict__ BT,
    const float* __restrict__ bias, float* __restrict__ C,
    __bf16* __restrict__ Cb, __bf16* __restrict__ Vt, int M, int N, int K,
    long btStride, long bStride, long cStride) {
  // XCD swizzle: each XCD owns a contiguous y-chunk; x fastest, z slowest.
  int gx = gridDim.x, gy = gridDim.y;
  int lin = blockIdx.x + gx * (blockIdx.y + gy * blockIdx.z);
  int xcd = lin & 7, li = lin >> 3;
  int yc = gy >> 3;
  int bx = li % gx;
  int t2 = li / gx;
  int by = xcd * yc + (t2 % yc);
  int z = t2 / yc;

  if (SK == 1) {
    if (KVM) {
      long idx = (long)(z >> 1) * 3 + 1 + (z & 1);
      BT += idx * btStride;
      bias += idx * bStride;
    } else {
      BT += (size_t)z * btStride;
      bias += (size_t)z * bStride;
    }
  }
  if (WF32) C += (size_t)z * cStride;
  if (WBF16) Cb += (size_t)z * cStride;

  constexpr int NI = BN / 32;
  __shared__ __bf16 As[2][128 * 64];
  __shared__ __bf16 Bs[2][BN * 64];

  int tid = threadIdx.x;
  int wave = tid >> 6, lane = tid & 63;
  int wm = wave >> 1, wn = wave & 1;           // 2 x 2 wave grid
  int quad = lane >> 4, l16 = lane & 15;
  int rlane = lane >> 3, c8 = lane & 7;
  int m0 = by * 128, n0 = bx * BN;
  int gcol = ((c8 ^ rlane) * 8);

  f32x4 acc[4][NI];
#pragma unroll
  for (int i = 0; i < 4; ++i)
#pragma unroll
    for (int j = 0; j < NI; ++j) acc[i][j] = (f32x4){0.f, 0.f, 0.f, 0.f};

  auto stage = [&](int buf, int k0) {
#pragma unroll
    for (int j = 0; j < 4; ++j) {
      int rb = j * 32 + wave * 8;
      load16_lds(&A[(size_t)(m0 + rb + rlane) * K + k0 + gcol],
                 &As[buf][rb * 64]);
    }
#pragma unroll
    for (int j = 0; j < BN / 32; ++j) {
      int rb = j * 32 + wave * 8;
      load16_lds(&BT[(size_t)(n0 + rb + rlane) * K + k0 + gcol],
                 &Bs[buf][rb * 64]);
    }
  };

  int kLen = (SK > 1) ? (K / SK) : K;
  int kBeg = (SK > 1) ? z * kLen : 0;
  const int NT = kLen >> 6;
  stage(0, kBeg);
  __syncthreads();
  for (int t = 0; t < NT; ++t) {
    int cur = t & 1;
    if (t + 1 < NT) stage(cur ^ 1, kBeg + ((t + 1) << 6));
#pragma unroll
    for (int kk = 0; kk < 64; kk += 32) {
      bf16x8 af[4], bfr[NI];
#pragma unroll
      for (int i = 0; i < 4; ++i) {
        int row = wm * 64 + i * 16 + l16;
        af[i] = *(const bf16x8*)&As[cur][row * 64 + ((((kk >> 3) + quad) ^ (row & 7)) * 8)];
      }
#pragma unroll
      for (int i = 0; i < NI; ++i) {
        int row = wn * (BN / 2) + i * 16 + l16;
        bfr[i] = *(const bf16x8*)&Bs[cur][row * 64 + ((((kk >> 3) + quad) ^ (row & 7)) * 8)];
      }
#pragma unroll
      for (int mi = 0; mi < 4; ++mi)
#pragma unroll
        for (int ni = 0; ni < NI; ++ni)
          acc[mi][ni] = __builtin_amdgcn_mfma_f32_16x16x32_bf16(
              af[mi], bfr[ni], acc[mi][ni], 0, 0, 0);
    }
    __syncthreads();
  }

#pragma unroll
  for (int ni = 0; ni < NI; ++ni) {
    int col = n0 + wn * (BN / 2) + ni * 16 + l16;
    float bv = (SK == 1 || z == 0) ? bias[col] : 0.f;
    if (TRV && z == 2) {
      int b = m0 >> 9;
#pragma unroll
      for (int mi = 0; mi < 4; ++mi) {
        int srow = (m0 & 511) + wm * 64 + mi * 16 + quad * 4;
        bf16x4 pk;
#pragma unroll
        for (int r = 0; r < 4; ++r) pk[r] = (__bf16)(acc[mi][ni][r] + bv);
        *(bf16x4*)&Vt[((size_t)(b * 512 + col)) * 512 + srow] = pk;
      }
    } else {
#pragma unroll
      for (int mi = 0; mi < 4; ++mi) {
#pragma unroll
        for (int r = 0; r < 4; ++r) {
          int row = m0 + wm * 64 + mi * 16 + quad * 4 + r;
          float v = acc[mi][ni][r] + bv;
          if (RELU) v = fmaxf(v, 0.f);
          if (WF32) C[(size_t)row * N + col] = v;
          if (WBF16) Cb[(size_t)row * N + col] = (__bf16)v;
        }
      }
    }
  }
}

// ---------------- MFMA encoder attention (R3 16-row version) -----
#define SCP 520
__global__ __launch_bounds__(256) void attn_mfma(const __bf16* __restrict__ QKV,
                                                 const __bf16* __restrict__ Vt,
                                                 float* __restrict__ O) {
  __shared__ __bf16 Sc[16 * SCP];
  __shared__ __bf16 Tt[2][64 * 64];

  const long ACTL = (long)NB * SEQ * DM;
  int tid = threadIdx.x;
  int wave = tid >> 6, lane = tid & 63;
  int quad = lane >> 4, l16 = lane & 15;
  int rlane = lane >> 3, c8 = lane & 7;
  // XCD swizzle: chunk by bh so each XCD's L2 holds few K/V panels.
  int lin = blockIdx.x + gridDim.x * blockIdx.y;
  int xcd = lin & 7, li = lin >> 3;
  int yc = gridDim.y >> 3;
  int q0 = (li % gridDim.x) * 16;
  int bh = xcd * yc + li / gridDim.x;
  int b = bh >> 3, h = bh & 7;
  const __bf16* Q = QKV;
  const __bf16* Kp = QKV + ACTL;
  size_t baseQ = ((size_t)b * SEQ + q0) * DM + h * DK;
  size_t baseK = ((size_t)b * SEQ) * DM + h * DK;
  const __bf16* VtB = Vt + ((size_t)(b * 512 + h * 64)) * 512;
  int gcol = (c8 ^ rlane) * 8;

  bf16x8 af0 = *(const bf16x8*)&Q[baseQ + (size_t)l16 * DM + quad * 8];
  bf16x8 af1 = *(const bf16x8*)&Q[baseQ + (size_t)l16 * DM + 32 + quad * 8];

  auto stageK = [&](int buf, int kt) {
#pragma unroll
    for (int j = 0; j < 2; ++j) {
      int row = j * 32 + wave * 8 + rlane;
      load16_lds(&Kp[baseK + (size_t)(kt * 64 + row) * DM + gcol],
                 &Tt[buf][(j * 32 + wave * 8) * 64]);
    }
  };
  auto stageV = [&](int buf, int kt) {
#pragma unroll
    for (int j = 0; j < 2; ++j) {
      int row = j * 32 + wave * 8 + rlane;
      load16_lds(&VtB[(size_t)row * 512 + kt * 64 + gcol],
                 &Tt[buf][(j * 32 + wave * 8) * 64]);
    }
  };

  // ---- QK^T, 8 tiles, prefetch-1 ----
  stageK(0, 0);
  __syncthreads();
  for (int kt = 0; kt < 8; ++kt) {
    int cur = kt & 1;
    if (kt < 7) stageK(cur ^ 1, kt + 1);
    f32x4 acc = (f32x4){0.f, 0.f, 0.f, 0.f};
    int krow = wave * 16 + l16, sw = krow & 7;
    bf16x8 b0 = *(const bf16x8*)&Tt[cur][krow * 64 + ((quad ^ sw) * 8)];
    bf16x8 b1 = *(const bf16x8*)&Tt[cur][krow * 64 + (((4 + quad) ^ sw) * 8)];
    acc = __builtin_amdgcn_mfma_f32_16x16x32_bf16(af0, b0, acc, 0, 0, 0);
    acc = __builtin_amdgcn_mfma_f32_16x16x32_bf16(af1, b1, acc, 0, 0, 0);
#pragma unroll
    for (int r = 0; r < 4; ++r)
      Sc[(quad * 4 + r) * SCP + kt * 64 + wave * 16 + l16] =
          (__bf16)(acc[r] * 0.125f);
    __syncthreads();
  }

  // prefetch first V tile under softmax
  stageV(0, 0);

  // ---- softmax over 16 rows ----
#pragma unroll
  for (int rr = 0; rr < 4; ++rr) {
    int r = wave * 4 + rr;
    float v[8];
    float mx = -1e30f;
#pragma unroll
    for (int j = 0; j < 8; ++j) {
      v[j] = (float)Sc[r * SCP + j * 64 + lane];
      mx = fmaxf(mx, v[j]);
    }
    for (int o = 32; o > 0; o >>= 1) mx = fmaxf(mx, __shfl_xor(mx, o));
    float sum = 0.f;
#pragma unroll
    for (int j = 0; j < 8; ++j) { v[j] = __expf(v[j] - mx); sum += v[j]; }
    for (int o = 32; o > 0; o >>= 1) sum += __shfl_xor(sum, o);
    float inv = 1.f / sum;
#pragma unroll
    for (int j = 0; j < 8; ++j)
      Sc[r * SCP + j * 64 + lane] = (__bf16)(v[j] * inv);
  }
  __syncthreads();  // softmax Sc visible + V tile 0 staged (vmcnt drain)

  // ---- PV, 8 tiles, prefetch-1 ----
  f32x4 oacc = (f32x4){0.f, 0.f, 0.f, 0.f};
  for (int kt = 0; kt < 8; ++kt) {
    int cur = kt & 1;
    if (kt < 7) stageV(cur ^ 1, kt + 1);
    int drow = wave * 16 + l16, sw = drow & 7;
#pragma unroll
    for (int kk = 0; kk < 64; kk += 32) {
      bf16x8 pa = *(const bf16x8*)&Sc[l16 * SCP + kt * 64 + kk + quad * 8];
      bf16x8 vb = *(const bf16x8*)&Tt[cur][drow * 64 + ((((kk >> 3) + quad) ^ sw) * 8)];
      oacc = __builtin_amdgcn_mfma_f32_16x16x32_bf16(pa, vb, oacc, 0, 0, 0);
    }
    __syncthreads();
  }
#pragma unroll
  for (int r = 0; r < 4; ++r)
    O[((size_t)b * SEQ + q0 + quad * 4 + r) * DM + h * DK + wave * 16 + l16] =
        oacc[r];
}

// ---------------- residual + layernorm (optional second summand x2) -------
template <bool WB>
__global__ __launch_bounds__(256) void add_ln(
    const float* __restrict__ x, const float* __restrict__ x2,
    const float* __restrict__ res, const float* __restrict__ cbias,
    const float* __restrict__ g, const float* __restrict__ beta,
    float* __restrict__ y, __bf16* __restrict__ yb) {
  int row = blockIdx.x;
  int tid = threadIdx.x;
  const float* xr = x + (size_t)row * DM;
  const float* rr = res + (size_t)row * DM;
  float b0 = cbias ? cbias[tid] : 0.f;
  float b1 = cbias ? cbias[tid + 256] : 0.f;
  float v0 = xr[tid] + b0 + rr[tid];
  float v1 = xr[tid + 256] + b1 + rr[tid + 256];
  if (x2) {
    const float* x2r = x2 + (size_t)row * DM;
    v0 += x2r[tid];
    v1 += x2r[tid + 256];
  }
  float s = v0 + v1, sq = v0 * v0 + v1 * v1;
  for (int o = 32; o > 0; o >>= 1) {
    s += __shfl_xor(s, o);
    sq += __shfl_xor(sq, o);
  }
  __shared__ float ps[4], pq[4];
  int wv = tid >> 6;
  if ((tid & 63) == 0) { ps[wv] = s; pq[wv] = sq; }
  __syncthreads();
  s = ps[0] + ps[1] + ps[2] + ps[3];
  sq = pq[0] + pq[1] + pq[2] + pq[3];
  float mean = s * (1.f / DM);
  float var = sq * (1.f / DM) - mean * mean;
  float rstd = rsqrtf(var + 1e-5f);
  float o0 = (v0 - mean) * rstd * g[tid] + beta[tid];
  float o1 = (v1 - mean) * rstd * g[tid + 256] + beta[tid + 256];
  y[(size_t)row * DM + tid] = o0;
  y[(size_t)row * DM + tid + 256] = o1;
  if (WB) {
    yb[(size_t)row * DM + tid] = (__bf16)o0;
    yb[(size_t)row * DM + tid + 256] = (__bf16)o1;
  }
}

// ============ fused decoder (3 dispatches/layer) ============
// Flow per layer i:
//   dd   = LN3_{i-1}(df + x2)   (or embed for i==0)        [recomputed]
//   t    = LN1(dd + dd@Wv + bv)                             [dec_attn]
//   da   = attn(t@Wq+bq, K, V)                              [dec_attn]
//   x2   = LN2(da + t)                                      [dec_ffn1f]
//   h    = relu(x2@W1 + b1)                                 [dec_ffn1f]
//   df   = h@W2 + b2                                        [dec_ffn2]
// Final: out = LN3_5(df + x2) @ Wo + ob                     [dec_outf]

// one block per (b,h); LN1/LN3 recomputed redundantly per block (cheap)
template <bool FIRST>
__global__ __launch_bounds__(256) void dec_attn(
    const float* __restrict__ dfp, const float* __restrict__ xp,
    const float* __restrict__ g3, const float* __restrict__ b3,
    const int* __restrict__ target, const float* __restrict__ emb,
    const __bf16* __restrict__ WvT, const float* __restrict__ bv,
    const float* __restrict__ g1, const float* __restrict__ b1ln,
    const __bf16* __restrict__ WqT, const float* __restrict__ qb,
    const __bf16* __restrict__ Kb, const __bf16* __restrict__ Vb,
    float* __restrict__ da, float* __restrict__ tbuf) {
  __shared__ float arow[DM];
  __shared__ float trow[DM];
  __shared__ float red[4][64];
  __shared__ float q[64];
  __shared__ float sc[SEQ];
  __shared__ float wred[4];
  __shared__ float ps[4], pq[4];

  int bh = blockIdx.x, b = bh >> 3, h = bh & 7;
  int tid = threadIdx.x, lane = tid & 63, wave = tid >> 6;

  // ---- dd (layer input) ----
  if (FIRST) {
    int tok = target[b];
    arow[tid] = emb[(size_t)tok * DM + tid] * EMB_SCALE + ((tid & 1) ? 1.f : 0.f);
    arow[tid + 256] =
        emb[(size_t)tok * DM + tid + 256] * EMB_SCALE + ((tid & 1) ? 1.f : 0.f);
    __syncthreads();
  } else {
    float v0 = dfp[(size_t)b * DM + tid] + xp[(size_t)b * DM + tid];
    float v1 = dfp[(size_t)b * DM + tid + 256] + xp[(size_t)b * DM + tid + 256];
    ln_pair(v0, v1, tid, g3, b3, arow, ps, pq);
  }

  // ---- t = LN1(dd + dd@Wv + bv) ----
  float o0, o1;
  {
    const __bf16* w = &WvT[(size_t)tid * DM];
    float acc = 0.f;
#pragma unroll 4
    for (int k = 0; k < DM; k += 8) acc += dot8(*(const bf16x8*)&w[k], &arow[k]);
    o0 = arow[tid] + acc + bv[tid];
  }
  {
    const __bf16* w = &WvT[(size_t)(tid + 256) * DM];
    float acc = 0.f;
#pragma unroll 4
    for (int k = 0; k < DM; k += 8) acc += dot8(*(const bf16x8*)&w[k], &arow[k]);
    o1 = arow[tid + 256] + acc + bv[tid + 256];
  }
  ln_pair(o0, o1, tid, g1, b1ln, trow, ps, pq);
  if (h == 0) {
    tbuf[(size_t)b * DM + tid] = trow[tid];
    tbuf[(size_t)b * DM + tid + 256] = trow[tid + 256];
  }

  // ---- q-gemv: 64 cols x 4 k-subs from trow ----
  {
    int c = tid & 63, s = tid >> 6;
    const __bf16* w = &WqT[(size_t)(h * 64 + c) * DM + s * 128];
    float acc = 0.f;
#pragma unroll
    for (int k = 0; k < 128; k += 8)
      acc += dot8(*(const bf16x8*)&w[k], &trow[s * 128 + k]);
    red[s][c] = acc;
  }
  __syncthreads();
  if (tid < 64)
    q[tid] = red[0][tid] + red[1][tid] + red[2][tid] + red[3][tid] + qb[h * 64 + tid];
  __syncthreads();

  // ---- scores ----
  for (int key = tid; key < SEQ; key += 256) {
    const __bf16* kp = &Kb[((size_t)b * SEQ + key) * DM + h * 64];
    float acc = 0.f;
#pragma unroll
    for (int k = 0; k < 64; k += 8) acc += dot8(*(const bf16x8*)&kp[k], &q[k]);
    sc[key] = acc * 0.125f;
  }
  __syncthreads();
  float m = -1e30f;
  for (int j = tid; j < SEQ; j += 256) m = fmaxf(m, sc[j]);
  for (int o = 32; o > 0; o >>= 1) m = fmaxf(m, __shfl_xor(m, o));
  if (lane == 0) wred[wave] = m;
  __syncthreads();
  m = fmaxf(fmaxf(wred[0], wred[1]), fmaxf(wred[2], wred[3]));
  float sum = 0.f;
  for (int j = tid; j < SEQ; j += 256) {
    float p = __expf(sc[j] - m);
    sc[j] = p;
    sum += p;
  }
  for (int o = 32; o > 0; o >>= 1) sum += __shfl_xor(sum, o);
  __syncthreads();   // sc writes done before reuse of wred
  if (lane == 0) wred[wave] = sum;
  __syncthreads();
  float inv = 1.f / (wred[0] + wred[1] + wred[2] + wred[3]);

  // ---- PV ----
  {
    int d = tid & 63, s = tid >> 6;
    float acc = 0.f;
    const __bf16* vp = &Vb[((size_t)b * SEQ + s * 128) * DM + h * 64 + d];
#pragma unroll 8
    for (int k = 0; k < 128; ++k) acc += sc[s * 128 + k] * (float)vp[(size_t)k * DM];
    red[s][d] = acc;
  }
  __syncthreads();
  if (tid < 64)
    da[(size_t)b * DM + h * 64 + tid] =
        (red[0][tid] + red[1][tid] + red[2][tid] + red[3][tid]) * inv;
}

// x2 = LN2(da + t) recomputed per block; h = relu(x2@W1+b1); blk0 saves x2
__global__ __launch_bounds__(256) void dec_ffn1f(
    const float* __restrict__ da, const float* __restrict__ tbuf,
    const float* __restrict__ g2, const float* __restrict__ b2ln,
    const __bf16* __restrict__ W1T, const float* __restrict__ b1,
    float* __restrict__ h, float* __restrict__ xbuf) {
  __shared__ float a[8][DM];
  __shared__ float ps[4], pq[4];
  int tid = threadIdx.x, lane = tid & 63, wave = tid >> 6;
  for (int r = 0; r < 8; ++r) {
    float v0 = da[(size_t)r * DM + tid] + tbuf[(size_t)r * DM + tid];
    float v1 = da[(size_t)r * DM + tid + 256] + tbuf[(size_t)r * DM + tid + 256];
    ln_pair(v0, v1, tid, g2, b2ln, a[r], ps, pq);
  }
  int col = blockIdx.x * 4 + wave;
  bf16x8 w = *(const bf16x8*)&W1T[(size_t)col * DM + lane * 8];
  float acc[8];
#pragma unroll
  for (int r = 0; r < 8; ++r) acc[r] = dot8(w, &a[r][lane * 8]);
#pragma unroll
  for (int r = 0; r < 8; ++r)
    for (int o = 32; o > 0; o >>= 1) acc[r] += __shfl_xor(acc[r], o);
  if (lane == 0) {
    float bb = b1[col];
#pragma unroll
    for (int r = 0; r < 8; ++r) h[(size_t)r * DFF + col] = fmaxf(acc[r] + bb, 0.f);
  }
  if (blockIdx.x == 0) {
#pragma unroll
    for (int r = 0; r < 8; ++r) {
      xbuf[(size_t)r * DM + tid] = a[r][tid];
      xbuf[(size_t)r * DM + tid + 256] = a[r][tid + 256];
    }
  }
}

// df[r][col] = h[r] @ W2T[col] + b2[col]; 2 cols/block, 2 waves per col
__global__ __launch_bounds__(256) void dec_ffn2(
    const float* __restrict__ h, const __bf16* __restrict__ W2T,
    const float* __restrict__ b2, float* __restrict__ df) {
  __shared__ float red[4][8];
  int tid = threadIdx.x, lane = tid & 63, wave = tid >> 6;
  int c = wave >> 1, half = wave & 1;
  int col = blockIdx.x * 2 + c;
  int k0 = half * 1024 + lane * 8;
  bf16x8 w0 = *(const bf16x8*)&W2T[(size_t)col * DFF + k0];
  bf16x8 w1 = *(const bf16x8*)&W2T[(size_t)col * DFF + k0 + 512];
  float acc[8];
#pragma unroll
  for (int r = 0; r < 8; ++r) {
    float4 h0a = *(const float4*)&h[(size_t)r * DFF + k0];
    float4 h0b = *(const float4*)&h[(size_t)r * DFF + k0 + 4];
    float4 h1a = *(const float4*)&h[(size_t)r * DFF + k0 + 512];
    float4 h1b = *(const float4*)&h[(size_t)r * DFF + k0 + 516];
    float hh0[8] = {h0a.x, h0a.y, h0a.z, h0a.w, h0b.x, h0b.y, h0b.z, h0b.w};
    float hh1[8] = {h1a.x, h1a.y, h1a.z, h1a.w, h1b.x, h1b.y, h1b.z, h1b.w};
    acc[r] = dot8(w0, hh0) + dot8(w1, hh1);
  }
#pragma unroll
  for (int r = 0; r < 8; ++r)
    for (int o = 32; o > 0; o >>= 1) acc[r] += __shfl_xor(acc[r], o);
  if (lane == 0) {
#pragma unroll
    for (int r = 0; r < 8; ++r) red[wave][r] = acc[r];
  }
  __syncthreads();
  if (tid < 16) {
    int cc = tid >> 3, r = tid & 7;
    int ocol = blockIdx.x * 2 + cc;
    df[(size_t)r * DM + ocol] =
        red[cc * 2][r] + red[cc * 2 + 1][r] + b2[ocol];
  }
}

// out = LN3_5(df + x2) @ Wo + ob  (LN recomputed per block)
__global__ __launch_bounds__(256) void dec_outf(
    const float* __restrict__ df, const float* __restrict__ xbuf,
    const float* __restrict__ g3, const float* __restrict__ b3,
    const __bf16* __restrict__ WoT, const float* __restrict__ ob,
    float* __restrict__ out) {
  __shared__ float a[8][DM];
  __shared__ float ps[4], pq[4];
  int tid = threadIdx.x, lane = tid & 63, wave = tid >> 6;
  for (int r = 0; r < 8; ++r) {
    float v0 = df[(size_t)r * DM + tid] + xbuf[(size_t)r * DM + tid];
    float v1 = df[(size_t)r * DM + tid + 256] + xbuf[(size_t)r * DM + tid + 256];
    ln_pair(v0, v1, tid, g3, b3, a[r], ps, pq);
  }
  int col = blockIdx.x * 4 + wave;
  bf16x8 w = *(const bf16x8*)&WoT[(size_t)col * DM + lane * 8];
  float acc[8];
#pragma unroll
  for (int r = 0; r < 8; ++r) acc[r] = dot8(w, &a[r][lane * 8]);
#pragma unroll
  for (int r = 0; r < 8; ++r)
    for (int o = 32; o > 0; o >>= 1) acc[r] += __shfl_xor(acc[r], o);
  if (lane == 0) {
    float bb = ob[col];
#pragma unroll
    for (int r = 0; r < 8; ++r) out[(size_t)r * OUTD + col] = acc[r] + bb;
  }
}

// ---------------------------------------------------------------------------
extern "C" void kernel_launch(void* const* d_in, const int* in_sizes, int n_in,
                              void* d_out, int out_size, void* d_ws, size_t ws_size,
                              hipStream_t stream) {
  const int* x = (const int*)d_in[0];
  const int* target = (const int*)d_in[1];
  const float* in_emb = (const float*)d_in[2];
  const float* out_emb = (const float*)d_in[3];
  const float* enc_qkv_w = (const float*)d_in[4];
  const float* enc_qkv_b = (const float*)d_in[5];
  const float* enc_ln1_g = (const float*)d_in[6];
  const float* enc_ln1_b = (const float*)d_in[7];
  const float* enc_ffn1_w = (const float*)d_in[8];
  const float* enc_ffn1_b = (const float*)d_in[9];
  const float* enc_ffn2_w = (const float*)d_in[10];
  const float* enc_ffn2_b = (const float*)d_in[11];
  const float* enc_ln2_g = (const float*)d_in[12];
  const float* enc_ln2_b = (const float*)d_in[13];
  const float* dec_qkv1_w = (const float*)d_in[14];
  const float* dec_qkv1_b = (const float*)d_in[15];
  const float* dec_ln1_g = (const float*)d_in[16];
  const float* dec_ln1_b = (const float*)d_in[17];
  const float* dec_qkv2_w = (const float*)d_in[18];
  const float* dec_qkv2_b = (const float*)d_in[19];
  const float* dec_ln2_g = (const float*)d_in[20];
  const float* dec_ln2_b = (const float*)d_in[21];
  const float* dec_ffn1_w = (const float*)d_in[22];
  const float* dec_ffn1_b = (const float*)d_in[23];
  const float* dec_ffn2_w = (const float*)d_in[24];
  const float* dec_ffn2_b = (const float*)d_in[25];
  const float* dec_ln3_g = (const float*)d_in[26];
  const float* dec_ln3_b = (const float*)d_in[27];
  const float* out_w = (const float*)d_in[28];
  const float* out_b = (const float*)d_in[29];

  const long ACTL = (long)NB * SEQ * DM;           // 2M elems
  const int M = NB * SEQ;                           // 4096
  const long WQS = (long)DM * DM;
  const long WFS = (long)DM * DFF;

  char* p = (char*)d_ws;
  float* e = (float*)p;            p += ACTL * 4;
  float* tb = (float*)p;           p += ACTL * 4;
  float* pe = (float*)p;           p += (long)SEQ * DM * 4;
  float* dd = (float*)p;           p += NB * DM * 4;
  float* da = (float*)p;           p += NB * DM * 4;
  float* dh = (float*)p;           p += NB * DFF * 4;
  float* df = (float*)p;           p += NB * DM * 4;
  p = (char*)(((uintptr_t)p + 255) & ~(uintptr_t)255);
  __bf16* eb = (__bf16*)p;         p += ACTL * 2;
  __bf16* qkvb = (__bf16*)p;       p += 3 * ACTL * 2;   // Q,K; slice 2 = V^T
  __bf16* hbb = (__bf16*)p;        p += (long)M * DFF * 2;
  __bf16* kvb = (__bf16*)p;        p += 12L * ACTL * 2; // [layer][K,V][4096][512]
  __bf16* wtq = (__bf16*)p;        p += 18L * WQS * 2;
  __bf16* wtf1 = (__bf16*)p;       p += 6L * WFS * 2;
  __bf16* wtf2 = (__bf16*)p;       p += 6L * WFS * 2;
  __bf16* wtd = (__bf16*)p;        p += 18L * WQS * 2;  // dec_qkv2^T
  __bf16* wtd1 = (__bf16*)p;       p += 18L * WQS * 2;  // dec_qkv1 V-slices^T (6 used)
  __bf16* wf1t = (__bf16*)p;       p += 6L * WFS * 2;
  __bf16* wf2t = (__bf16*)p;       p += 6L * WFS * 2;
  __bf16* wot = (__bf16*)p;        p += (long)OUTD * DM * 2;

  __bf16* vtb = qkvb + 2 * ACTL;
  // split-K partial-1 for encoder FFN2: reuse kvb region (idle until the
  // KV gemm after the encoder loop)
  float* tb2 = (float*)kvb;
  long tb2Off = (long)(tb2 - tb);  // element stride from partial0 to partial1
  // decoder scratch reuse: dd region holds t rows; pe region (dead after
  // embed_enc) holds x2 rows
  float* tbuf = dd;
  float* xbuf = pe;

  // ---- one-time prep ----
  pe_kernel<<<SEQ, 256, 0, stream>>>(pe);
  transpose_w<<<dim3(16, 16, 18), 256, 0, stream>>>(enc_qkv_w, wtq, DM, DM, 1, 0);
  transpose_w<<<dim3(64, 16, 6), 256, 0, stream>>>(enc_ffn1_w, wtf1, DM, DFF, 1, 0);
  transpose_w<<<dim3(16, 64, 6), 256, 0, stream>>>(enc_ffn2_w, wtf2, DFF, DM, 1, 0);
  transpose_w<<<dim3(16, 16, 18), 256, 0, stream>>>(dec_qkv2_w, wtd, DM, DM, 1, 0);
  transpose_w<<<dim3(16, 16, 6), 256, 0, stream>>>(dec_qkv1_w, wtd1, DM, DM, 3, 2);
  transpose_w<<<dim3(64, 16, 6), 256, 0, stream>>>(dec_ffn1_w, wf1t, DM, DFF, 1, 0);
  transpose_w<<<dim3(16, 64, 6), 256, 0, stream>>>(dec_ffn2_w, wf2t, DFF, DM, 1, 0);
  transpose_ow<<<dim3(32, 16), 256, 0, stream>>>(out_w, wot);

  // ---- encoder ----
  embed_enc<<<(M * DM) / 256, 256, 0, stream>>>(x, in_emb, pe, e, eb);
  for (int i = 0; i < NL; ++i) {
    mfma_gemm<64, 1, false, false, true, true, false><<<dim3(8, 32, 3), 256, 0, stream>>>(
        eb, wtq + (size_t)i * 3 * WQS, enc_qkv_b + (size_t)i * 3 * DM,
        nullptr, qkvb, vtb, M, DM, DM, WQS, DM, ACTL);
    attn_mfma<<<dim3(SEQ / 16, NB * NH), 256, 0, stream>>>(qkvb, vtb, tb);
    add_ln<true><<<M, 256, 0, stream>>>(tb, nullptr, e, nullptr,
                                        enc_ln1_g + i * DM, enc_ln1_b + i * DM,
                                        e, eb);
    mfma_gemm<64, 1, true, false, true, false, false><<<dim3(32, 32, 1), 256, 0, stream>>>(
        eb, wtf1 + (size_t)i * WFS, enc_ffn1_b + (size_t)i * DFF,
        nullptr, hbb, nullptr, M, DFF, DM, 0, 0, 0);
    mfma_gemm<64, 2, false, true, false, false, false><<<dim3(8, 32, 2), 256, 0, stream>>>(
        hbb, wtf2 + (size_t)i * WFS, enc_ffn2_b + (size_t)i * DM,
        tb, nullptr, nullptr, M, DM, DFF, 0, 0, tb2Off);
    add_ln<true><<<M, 256, 0, stream>>>(tb, tb2, e, nullptr,
                                        enc_ln2_g + i * DM, enc_ln2_b + i * DM,
                                        e, eb);
  }

  // ---- cross K/V for all 6 layers in one dispatch (bf16 out) ----
  mfma_gemm<64, 1, false, false, true, false, true><<<dim3(8, 32, 12), 256, 0, stream>>>(
      eb, wtd, dec_qkv2_b, nullptr, kvb, nullptr, M, DM, DM, WQS, DM, ACTL);

  // ---- decoder: 3 dispatches per layer ----
  for (int i = 0; i < NL; ++i) {
    const __bf16* Wv = wtd1 + (size_t)i * WQS;
    const float* bvp = dec_qkv1_b + ((size_t)i * 3 + 2) * DM;
    const __bf16* Wq = wtd + (size_t)i * 3 * WQS;
    const float* qbp = dec_qkv2_b + (size_t)i * 3 * DM;
    const __bf16* Kb = kvb + (size_t)i * 2 * ACTL;
    const __bf16* Vb = kvb + ((size_t)i * 2 + 1) * ACTL;
    if (i == 0)
      dec_attn<true><<<64, 256, 0, stream>>>(
          nullptr, nullptr, nullptr, nullptr, target, out_emb,
          Wv, bvp, dec_ln1_g + i * DM, dec_ln1_b + i * DM,
          Wq, qbp, Kb, Vb, da, tbuf);
    else
      dec_attn<false><<<64, 256, 0, stream>>>(
          df, xbuf, dec_ln3_g + (i - 1) * DM, dec_ln3_b + (i - 1) * DM,
          nullptr, nullptr,
          Wv, bvp, dec_ln1_g + i * DM, dec_ln1_b + i * DM,
          Wq, qbp, Kb, Vb, da, tbuf);
    dec_ffn1f<<<DFF / 4, 256, 0, stream>>>(
        da, tbuf, dec_ln2_g + i * DM, dec_ln2_b + i * DM,
        wf1t + (size_t)i * WFS, dec_ffn1_b + (size_t)i * DFF, dh, xbuf);
    dec_ffn2<<<DM / 2, 256, 0, stream>>>(
        dh, wf2t + (size_t)i * WFS, dec_ffn2_b + (size_t)i * DM, df);
  }

  // ---- output projection (LN3 + gemv + bias fused) ----
  dec_outf<<<OUTD / 4, 256, 0, stream>>>(df, xbuf, dec_ln3_g + 5 * DM,
                                         dec_ln3_b + 5 * DM, wot, out_b,
                                         (float*)d_out);
}

// Round 7
// 1114.079 us; speedup vs baseline: 1.0896x; 1.0113x over previous
//
#include <hip/hip_runtime.h>
#include <hip/hip_bf16.h>

#define DM 512
#define NH 8
#define DK 64
#define SEQ 512
#define NB 8
#define NL 6
#define DFF 2048
#define OUTD 1000
#define EMB_SCALE 22.627416997969522f
#define PE_C (-0.017988946039015984f)   // -ln(10000)/512

typedef __bf16 bf16x8 __attribute__((ext_vector_type(8)));
typedef __bf16 bf16x4 __attribute__((ext_vector_type(4)));
typedef float f32x4 __attribute__((ext_vector_type(4)));

__device__ __forceinline__ void load16_lds(const __bf16* g, __bf16* l) {
  __builtin_amdgcn_global_load_lds(
      (const __attribute__((address_space(1))) void*)g,
      (__attribute__((address_space(3))) void*)l, 16, 0, 0);
}

__device__ __forceinline__ float dot8(bf16x8 w, const float* a) {
  float s = 0.f;
#pragma unroll
  for (int j = 0; j < 8; ++j) s += (float)w[j] * a[j];
  return s;
}

// block-wide LN over a 512-elem row held as (v0 @ tid, v1 @ tid+256).
// writes normalized row into out[0..511]; trailing sync makes it visible.
__device__ __forceinline__ void ln_pair(float v0, float v1, int tid,
                                        const float* __restrict__ g,
                                        const float* __restrict__ beta,
                                        float* out, float* ps, float* pq) {
  float s = v0 + v1, sq = v0 * v0 + v1 * v1;
  for (int o = 32; o > 0; o >>= 1) { s += __shfl_xor(s, o); sq += __shfl_xor(sq, o); }
  int wv = tid >> 6;
  if ((tid & 63) == 0) { ps[wv] = s; pq[wv] = sq; }
  __syncthreads();
  s = ps[0] + ps[1] + ps[2] + ps[3];
  sq = pq[0] + pq[1] + pq[2] + pq[3];
  float mean = s * (1.f / DM);
  float rstd = rsqrtf(sq * (1.f / DM) - mean * mean + 1e-5f);
  out[tid] = (v0 - mean) * rstd * g[tid] + beta[tid];
  out[tid + 256] = (v1 - mean) * rstd * g[tid + 256] + beta[tid + 256];
  __syncthreads();
}

// ---------------- PE table ----------------
__global__ __launch_bounds__(256) void pe_kernel(float* __restrict__ pe) {
  int s = blockIdx.x;
  int d2 = threadIdx.x;
  float div = expf((float)(2 * d2) * PE_C);
  float arg = (float)s * div;
  pe[(size_t)s * DM + 2 * d2] = sinf(arg);
  pe[(size_t)s * DM + 2 * d2 + 1] = cosf(arg);
}

// ---------------- embedding (float2 vectorized) ----------------
__global__ __launch_bounds__(256) void embed_enc(const int* __restrict__ x,
                                                 const float* __restrict__ emb,
                                                 const float* __restrict__ pe,
                                                 float* __restrict__ e,
                                                 __bf16* __restrict__ eb) {
  int idx = blockIdx.x * 256 + threadIdx.x;   // 2-elem granule index
  int d2 = idx & 255;                         // 256 granules per row
  int bs = idx >> 8;
  int s = bs & (SEQ - 1);
  int tok = x[bs];
  float2 ev = ((const float2*)(emb + (size_t)tok * DM))[d2];
  float2 pv = ((const float2*)(pe + (size_t)s * DM))[d2];
  float v0 = ev.x * EMB_SCALE + pv.x;
  float v1 = ev.y * EMB_SCALE + pv.y;
  ((float2*)e)[idx] = make_float2(v0, v1);
  union { __bf16 h[2]; unsigned u; } pk;
  pk.h[0] = (__bf16)v0; pk.h[1] = (__bf16)v1;
  ((unsigned*)eb)[idx] = pk.u;
}

// ---------------- merged weight transpose fp32[K][N] -> bf16[N][K] ---------
// three source/dest groups selected by z; group 2 takes input slice
// z2*zmul2+zadd2 (for dec_qkv1 V-slices)
__global__ __launch_bounds__(256) void transpose_w3(
    const float* __restrict__ W0, __bf16* __restrict__ T0, int n0,
    const float* __restrict__ W1, __bf16* __restrict__ T1, int n1,
    const float* __restrict__ W2, __bf16* __restrict__ T2,
    long zmul2, long zadd2, int K, int N) {
  __shared__ float t[32][33];
  int z = blockIdx.z;
  const float* W;
  __bf16* WT;
  if (z < n0) {
    W = W0 + (size_t)z * K * N; WT = T0 + (size_t)z * K * N;
  } else if (z < n0 + n1) {
    int zz = z - n0;
    W = W1 + (size_t)zz * K * N; WT = T1 + (size_t)zz * K * N;
  } else {
    int zz = z - n0 - n1;
    W = W2 + (size_t)(zz * zmul2 + zadd2) * K * N;
    WT = T2 + (size_t)zz * K * N;
  }
  int k0 = blockIdx.y * 32, n0b = blockIdx.x * 32;
  int tx = threadIdx.x & 7, ty = threadIdx.x >> 3;
  float4 v = *(const float4*)&W[(size_t)(k0 + ty) * N + n0b + tx * 4];
  t[ty][tx * 4 + 0] = v.x; t[ty][tx * 4 + 1] = v.y;
  t[ty][tx * 4 + 2] = v.z; t[ty][tx * 4 + 3] = v.w;
  __syncthreads();
  bf16x4 o;
  o[0] = (__bf16)t[tx * 4 + 0][ty];
  o[1] = (__bf16)t[tx * 4 + 1][ty];
  o[2] = (__bf16)t[tx * 4 + 2][ty];
  o[3] = (__bf16)t[tx * 4 + 3][ty];
  *(bf16x4*)&WT[(size_t)(n0b + ty) * K + k0 + tx * 4] = o;
}

// out_w fp32 [512][1000] -> bf16 [1000][512] (guarded tail)
__global__ __launch_bounds__(256) void transpose_ow(const float* __restrict__ W,
                                                    __bf16* __restrict__ WT) {
  __shared__ float t[32][33];
  int n0 = blockIdx.x * 32, k0 = blockIdx.y * 32;
  int tid = threadIdx.x;
  for (int i = tid; i < 1024; i += 256) {
    int kk = i >> 5, nn = i & 31;
    t[kk][nn] = (n0 + nn < OUTD) ? W[(size_t)(k0 + kk) * OUTD + n0 + nn] : 0.f;
  }
  __syncthreads();
  for (int i = tid; i < 1024; i += 256) {
    int nn = i >> 5, kk = i & 31;
    if (n0 + nn < OUTD)
      WT[(size_t)(n0 + nn) * DM + k0 + kk] = (__bf16)t[kk][nn];
  }
}

// ---------------- MFMA GEMM: 256 thr / 4 waves, BM=128 x BN=64 tiles,
// per-wave 64x32 output (acc[4][2]), dbuf staging (T3 2-phase), XCD swizzle.
// LDS 48KB -> 3 blocks/CU (R3 structure: proven best).
template <int BN, int SK, bool RELU, bool WF32, bool WBF16, bool TRV, bool KVM>
__global__ __launch_bounds__(256) void mfma_gemm(
    const __bf16* __restrict__ A, const __bf16* __restrict__ BT,
    const float* __restrict__ bias, float* __restrict__ C,
    __bf16* __restrict__ Cb, __bf16* __restrict__ Vt, int M, int N, int K,
    long btStride, long bStride, long cStride) {
  // XCD swizzle: each XCD owns a contiguous y-chunk; x fastest, z slowest.
  int gx = gridDim.x, gy = gridDim.y;
  int lin = blockIdx.x + gx * (blockIdx.y + gy * blockIdx.z);
  int xcd = lin & 7, li = lin >> 3;
  int yc = gy >> 3;
  int bx = li % gx;
  int t2 = li / gx;
  int by = xcd * yc + (t2 % yc);
  int z = t2 / yc;

  if (SK == 1) {
    if (KVM) {
      long idx = (long)(z >> 1) * 3 + 1 + (z & 1);
      BT += idx * btStride;
      bias += idx * bStride;
    } else {
      BT += (size_t)z * btStride;
      bias += (size_t)z * bStride;
    }
  }
  if (WF32) C += (size_t)z * cStride;
  if (WBF16) Cb += (size_t)z * cStride;

  constexpr int NI = BN / 32;
  __shared__ __bf16 As[2][128 * 64];
  __shared__ __bf16 Bs[2][BN * 64];

  int tid = threadIdx.x;
  int wave = tid >> 6, lane = tid & 63;
  int wm = wave >> 1, wn = wave & 1;           // 2 x 2 wave grid
  int quad = lane >> 4, l16 = lane & 15;
  int rlane = lane >> 3, c8 = lane & 7;
  int m0 = by * 128, n0 = bx * BN;
  int gcol = ((c8 ^ rlane) * 8);

  f32x4 acc[4][NI];
#pragma unroll
  for (int i = 0; i < 4; ++i)
#pragma unroll
    for (int j = 0; j < NI; ++j) acc[i][j] = (f32x4){0.f, 0.f, 0.f, 0.f};

  auto stage = [&](int buf, int k0) {
#pragma unroll
    for (int j = 0; j < 4; ++j) {
      int rb = j * 32 + wave * 8;
      load16_lds(&A[(size_t)(m0 + rb + rlane) * K + k0 + gcol],
                 &As[buf][rb * 64]);
    }
#pragma unroll
    for (int j = 0; j < BN / 32; ++j) {
      int rb = j * 32 + wave * 8;
      load16_lds(&BT[(size_t)(n0 + rb + rlane) * K + k0 + gcol],
                 &Bs[buf][rb * 64]);
    }
  };

  int kLen = (SK > 1) ? (K / SK) : K;
  int kBeg = (SK > 1) ? z * kLen : 0;
  const int NT = kLen >> 6;
  stage(0, kBeg);
  __syncthreads();
  for (int t = 0; t < NT; ++t) {
    int cur = t & 1;
    if (t + 1 < NT) stage(cur ^ 1, kBeg + ((t + 1) << 6));
#pragma unroll
    for (int kk = 0; kk < 64; kk += 32) {
      bf16x8 af[4], bfr[NI];
#pragma unroll
      for (int i = 0; i < 4; ++i) {
        int row = wm * 64 + i * 16 + l16;
        af[i] = *(const bf16x8*)&As[cur][row * 64 + ((((kk >> 3) + quad) ^ (row & 7)) * 8)];
      }
#pragma unroll
      for (int i = 0; i < NI; ++i) {
        int row = wn * (BN / 2) + i * 16 + l16;
        bfr[i] = *(const bf16x8*)&Bs[cur][row * 64 + ((((kk >> 3) + quad) ^ (row & 7)) * 8)];
      }
#pragma unroll
      for (int mi = 0; mi < 4; ++mi)
#pragma unroll
        for (int ni = 0; ni < NI; ++ni)
          acc[mi][ni] = __builtin_amdgcn_mfma_f32_16x16x32_bf16(
              af[mi], bfr[ni], acc[mi][ni], 0, 0, 0);
    }
    __syncthreads();
  }

#pragma unroll
  for (int ni = 0; ni < NI; ++ni) {
    int col = n0 + wn * (BN / 2) + ni * 16 + l16;
    float bv = (SK == 1 || z == 0) ? bias[col] : 0.f;
    if (TRV && z == 2) {
      int b = m0 >> 9;
#pragma unroll
      for (int mi = 0; mi < 4; ++mi) {
        int srow = (m0 & 511) + wm * 64 + mi * 16 + quad * 4;
        bf16x4 pk;
#pragma unroll
        for (int r = 0; r < 4; ++r) pk[r] = (__bf16)(acc[mi][ni][r] + bv);
        *(bf16x4*)&Vt[((size_t)(b * 512 + col)) * 512 + srow] = pk;
      }
    } else {
#pragma unroll
      for (int mi = 0; mi < 4; ++mi) {
#pragma unroll
        for (int r = 0; r < 4; ++r) {
          int row = m0 + wm * 64 + mi * 16 + quad * 4 + r;
          float v = acc[mi][ni][r] + bv;
          if (RELU) v = fmaxf(v, 0.f);
          if (WF32) C[(size_t)row * N + col] = v;
          if (WBF16) Cb[(size_t)row * N + col] = (__bf16)v;
        }
      }
    }
  }
}

// ---------------- MFMA encoder attention (R3 16-row version) -----
#define SCP 520
__global__ __launch_bounds__(256) void attn_mfma(const __bf16* __restrict__ QKV,
                                                 const __bf16* __restrict__ Vt,
                                                 float* __restrict__ O) {
  __shared__ __bf16 Sc[16 * SCP];
  __shared__ __bf16 Tt[2][64 * 64];

  const long ACTL = (long)NB * SEQ * DM;
  int tid = threadIdx.x;
  int wave = tid >> 6, lane = tid & 63;
  int quad = lane >> 4, l16 = lane & 15;
  int rlane = lane >> 3, c8 = lane & 7;
  // XCD swizzle: chunk by bh so each XCD's L2 holds few K/V panels.
  int lin = blockIdx.x + gridDim.x * blockIdx.y;
  int xcd = lin & 7, li = lin >> 3;
  int yc = gridDim.y >> 3;
  int q0 = (li % gridDim.x) * 16;
  int bh = xcd * yc + li / gridDim.x;
  int b = bh >> 3, h = bh & 7;
  const __bf16* Q = QKV;
  const __bf16* Kp = QKV + ACTL;
  size_t baseQ = ((size_t)b * SEQ + q0) * DM + h * DK;
  size_t baseK = ((size_t)b * SEQ) * DM + h * DK;
  const __bf16* VtB = Vt + ((size_t)(b * 512 + h * 64)) * 512;
  int gcol = (c8 ^ rlane) * 8;

  bf16x8 af0 = *(const bf16x8*)&Q[baseQ + (size_t)l16 * DM + quad * 8];
  bf16x8 af1 = *(const bf16x8*)&Q[baseQ + (size_t)l16 * DM + 32 + quad * 8];

  auto stageK = [&](int buf, int kt) {
#pragma unroll
    for (int j = 0; j < 2; ++j) {
      int row = j * 32 + wave * 8 + rlane;
      load16_lds(&Kp[baseK + (size_t)(kt * 64 + row) * DM + gcol],
                 &Tt[buf][(j * 32 + wave * 8) * 64]);
    }
  };
  auto stageV = [&](int buf, int kt) {
#pragma unroll
    for (int j = 0; j < 2; ++j) {
      int row = j * 32 + wave * 8 + rlane;
      load16_lds(&VtB[(size_t)row * 512 + kt * 64 + gcol],
                 &Tt[buf][(j * 32 + wave * 8) * 64]);
    }
  };

  // ---- QK^T, 8 tiles, prefetch-1 ----
  stageK(0, 0);
  __syncthreads();
  for (int kt = 0; kt < 8; ++kt) {
    int cur = kt & 1;
    if (kt < 7) stageK(cur ^ 1, kt + 1);
    f32x4 acc = (f32x4){0.f, 0.f, 0.f, 0.f};
    int krow = wave * 16 + l16, sw = krow & 7;
    bf16x8 b0 = *(const bf16x8*)&Tt[cur][krow * 64 + ((quad ^ sw) * 8)];
    bf16x8 b1 = *(const bf16x8*)&Tt[cur][krow * 64 + (((4 + quad) ^ sw) * 8)];
    acc = __builtin_amdgcn_mfma_f32_16x16x32_bf16(af0, b0, acc, 0, 0, 0);
    acc = __builtin_amdgcn_mfma_f32_16x16x32_bf16(af1, b1, acc, 0, 0, 0);
#pragma unroll
    for (int r = 0; r < 4; ++r)
      Sc[(quad * 4 + r) * SCP + kt * 64 + wave * 16 + l16] =
          (__bf16)(acc[r] * 0.125f);
    __syncthreads();
  }

  // prefetch first V tile under softmax
  stageV(0, 0);

  // ---- softmax over 16 rows ----
#pragma unroll
  for (int rr = 0; rr < 4; ++rr) {
    int r = wave * 4 + rr;
    float v[8];
    float mx = -1e30f;
#pragma unroll
    for (int j = 0; j < 8; ++j) {
      v[j] = (float)Sc[r * SCP + j * 64 + lane];
      mx = fmaxf(mx, v[j]);
    }
    for (int o = 32; o > 0; o >>= 1) mx = fmaxf(mx, __shfl_xor(mx, o));
    float sum = 0.f;
#pragma unroll
    for (int j = 0; j < 8; ++j) { v[j] = __expf(v[j] - mx); sum += v[j]; }
    for (int o = 32; o > 0; o >>= 1) sum += __shfl_xor(sum, o);
    float inv = 1.f / sum;
#pragma unroll
    for (int j = 0; j < 8; ++j)
      Sc[r * SCP + j * 64 + lane] = (__bf16)(v[j] * inv);
  }
  __syncthreads();  // softmax Sc visible + V tile 0 staged (vmcnt drain)

  // ---- PV, 8 tiles, prefetch-1 ----
  f32x4 oacc = (f32x4){0.f, 0.f, 0.f, 0.f};
  for (int kt = 0; kt < 8; ++kt) {
    int cur = kt & 1;
    if (kt < 7) stageV(cur ^ 1, kt + 1);
    int drow = wave * 16 + l16, sw = drow & 7;
#pragma unroll
    for (int kk = 0; kk < 64; kk += 32) {
      bf16x8 pa = *(const bf16x8*)&Sc[l16 * SCP + kt * 64 + kk + quad * 8];
      bf16x8 vb = *(const bf16x8*)&Tt[cur][drow * 64 + ((((kk >> 3) + quad) ^ sw) * 8)];
      oacc = __builtin_amdgcn_mfma_f32_16x16x32_bf16(pa, vb, oacc, 0, 0, 0);
    }
    __syncthreads();
  }
#pragma unroll
  for (int r = 0; r < 4; ++r)
    O[((size_t)b * SEQ + q0 + quad * 4 + r) * DM + h * DK + wave * 16 + l16] =
        oacc[r];
}

// ---------------- residual + layernorm (float2 vectorized) -------
template <bool WB>
__global__ __launch_bounds__(256) void add_ln(
    const float* __restrict__ x, const float* __restrict__ x2,
    const float* __restrict__ res, const float* __restrict__ cbias,
    const float* __restrict__ g, const float* __restrict__ beta,
    float* __restrict__ y, __bf16* __restrict__ yb) {
  int row = blockIdx.x;
  int tid = threadIdx.x;                // one float2 (cols 2t,2t+1) per thread
  float2 xv = ((const float2*)(x + (size_t)row * DM))[tid];
  float2 rv = ((const float2*)(res + (size_t)row * DM))[tid];
  float v0 = xv.x + rv.x;
  float v1 = xv.y + rv.y;
  if (cbias) {
    float2 cb = ((const float2*)cbias)[tid];
    v0 += cb.x; v1 += cb.y;
  }
  if (x2) {
    float2 x2v = ((const float2*)(x2 + (size_t)row * DM))[tid];
    v0 += x2v.x; v1 += x2v.y;
  }
  float s = v0 + v1, sq = v0 * v0 + v1 * v1;
  for (int o = 32; o > 0; o >>= 1) {
    s += __shfl_xor(s, o);
    sq += __shfl_xor(sq, o);
  }
  __shared__ float ps[4], pq[4];
  int wv = tid >> 6;
  if ((tid & 63) == 0) { ps[wv] = s; pq[wv] = sq; }
  __syncthreads();
  s = ps[0] + ps[1] + ps[2] + ps[3];
  sq = pq[0] + pq[1] + pq[2] + pq[3];
  float mean = s * (1.f / DM);
  float var = sq * (1.f / DM) - mean * mean;
  float rstd = rsqrtf(var + 1e-5f);
  float2 gg = ((const float2*)g)[tid];
  float2 bb = ((const float2*)beta)[tid];
  float o0 = (v0 - mean) * rstd * gg.x + bb.x;
  float o1 = (v1 - mean) * rstd * gg.y + bb.y;
  ((float2*)(y + (size_t)row * DM))[tid] = make_float2(o0, o1);
  if (WB) {
    union { __bf16 h[2]; unsigned u; } pk;
    pk.h[0] = (__bf16)o0; pk.h[1] = (__bf16)o1;
    ((unsigned*)(yb + (size_t)row * DM))[tid] = pk.u;
  }
}

// ============ fused decoder (3 dispatches/layer) ============
// Flow per layer i:
//   dd   = LN3_{i-1}(df + x2)   (or embed for i==0)        [recomputed]
//   t    = LN1(dd + dd@Wv + bv)                             [dec_attn]
//   da   = attn(t@Wq+bq, K, V)                              [dec_attn]
//   x2   = LN2(da + t)                                      [dec_ffn1f]
//   h    = relu(x2@W1 + b1)                                 [dec_ffn1f]
//   df   = h@W2 + b2                                        [dec_ffn2]
// Final: out = LN3_5(df + x2) @ Wo + ob                     [dec_outf]

// one block per (b,h); LN1/LN3 recomputed redundantly per block (cheap)
template <bool FIRST>
__global__ __launch_bounds__(256) void dec_attn(
    const float* __restrict__ dfp, const float* __restrict__ xp,
    const float* __restrict__ g3, const float* __restrict__ b3,
    const int* __restrict__ target, const float* __restrict__ emb,
    const __bf16* __restrict__ WvT, const float* __restrict__ bv,
    const float* __restrict__ g1, const float* __restrict__ b1ln,
    const __bf16* __restrict__ WqT, const float* __restrict__ qb,
    const __bf16* __restrict__ Kb, const __bf16* __restrict__ Vb,
    float* __restrict__ da, float* __restrict__ tbuf) {
  __shared__ float arow[DM];
  __shared__ float trow[DM];
  __shared__ float red[4][64];
  __shared__ float q[64];
  __shared__ float sc[SEQ];
  __shared__ float wred[4];
  __shared__ float ps[4], pq[4];

  int bh = blockIdx.x, b = bh >> 3, h = bh & 7;
  int tid = threadIdx.x, lane = tid & 63, wave = tid >> 6;

  // ---- dd (layer input) ----
  if (FIRST) {
    int tok = target[b];
    arow[tid] = emb[(size_t)tok * DM + tid] * EMB_SCALE + ((tid & 1) ? 1.f : 0.f);
    arow[tid + 256] =
        emb[(size_t)tok * DM + tid + 256] * EMB_SCALE + ((tid & 1) ? 1.f : 0.f);
    __syncthreads();
  } else {
    float v0 = dfp[(size_t)b * DM + tid] + xp[(size_t)b * DM + tid];
    float v1 = dfp[(size_t)b * DM + tid + 256] + xp[(size_t)b * DM + tid + 256];
    ln_pair(v0, v1, tid, g3, b3, arow, ps, pq);
  }

  // ---- t = LN1(dd + dd@Wv + bv) ----
  float o0, o1;
  {
    const __bf16* w = &WvT[(size_t)tid * DM];
    float acc = 0.f;
#pragma unroll 4
    for (int k = 0; k < DM; k += 8) acc += dot8(*(const bf16x8*)&w[k], &arow[k]);
    o0 = arow[tid] + acc + bv[tid];
  }
  {
    const __bf16* w = &WvT[(size_t)(tid + 256) * DM];
    float acc = 0.f;
#pragma unroll 4
    for (int k = 0; k < DM; k += 8) acc += dot8(*(const bf16x8*)&w[k], &arow[k]);
    o1 = arow[tid + 256] + acc + bv[tid + 256];
  }
  ln_pair(o0, o1, tid, g1, b1ln, trow, ps, pq);
  if (h == 0) {
    tbuf[(size_t)b * DM + tid] = trow[tid];
    tbuf[(size_t)b * DM + tid + 256] = trow[tid + 256];
  }

  // ---- q-gemv: 64 cols x 4 k-subs from trow ----
  {
    int c = tid & 63, s = tid >> 6;
    const __bf16* w = &WqT[(size_t)(h * 64 + c) * DM + s * 128];
    float acc = 0.f;
#pragma unroll
    for (int k = 0; k < 128; k += 8)
      acc += dot8(*(const bf16x8*)&w[k], &trow[s * 128 + k]);
    red[s][c] = acc;
  }
  __syncthreads();
  if (tid < 64)
    q[tid] = red[0][tid] + red[1][tid] + red[2][tid] + red[3][tid] + qb[h * 64 + tid];
  __syncthreads();

  // ---- scores ----
  for (int key = tid; key < SEQ; key += 256) {
    const __bf16* kp = &Kb[((size_t)b * SEQ + key) * DM + h * 64];
    float acc = 0.f;
#pragma unroll
    for (int k = 0; k < 64; k += 8) acc += dot8(*(const bf16x8*)&kp[k], &q[k]);
    sc[key] = acc * 0.125f;
  }
  __syncthreads();
  float m = -1e30f;
  for (int j = tid; j < SEQ; j += 256) m = fmaxf(m, sc[j]);
  for (int o = 32; o > 0; o >>= 1) m = fmaxf(m, __shfl_xor(m, o));
  if (lane == 0) wred[wave] = m;
  __syncthreads();
  m = fmaxf(fmaxf(wred[0], wred[1]), fmaxf(wred[2], wred[3]));
  float sum = 0.f;
  for (int j = tid; j < SEQ; j += 256) {
    float p = __expf(sc[j] - m);
    sc[j] = p;
    sum += p;
  }
  for (int o = 32; o > 0; o >>= 1) sum += __shfl_xor(sum, o);
  __syncthreads();   // sc writes done before reuse of wred
  if (lane == 0) wred[wave] = sum;
  __syncthreads();
  float inv = 1.f / (wred[0] + wred[1] + wred[2] + wred[3]);

  // ---- PV ----
  {
    int d = tid & 63, s = tid >> 6;
    float acc = 0.f;
    const __bf16* vp = &Vb[((size_t)b * SEQ + s * 128) * DM + h * 64 + d];
#pragma unroll 8
    for (int k = 0; k < 128; ++k) acc += sc[s * 128 + k] * (float)vp[(size_t)k * DM];
    red[s][d] = acc;
  }
  __syncthreads();
  if (tid < 64)
    da[(size_t)b * DM + h * 64 + tid] =
        (red[0][tid] + red[1][tid] + red[2][tid] + red[3][tid]) * inv;
}

// x2 = LN2(da + t) recomputed per block; h = relu(x2@W1+b1); blk0 saves x2
__global__ __launch_bounds__(256) void dec_ffn1f(
    const float* __restrict__ da, const float* __restrict__ tbuf,
    const float* __restrict__ g2, const float* __restrict__ b2ln,
    const __bf16* __restrict__ W1T, const float* __restrict__ b1,
    float* __restrict__ h, float* __restrict__ xbuf) {
  __shared__ float a[8][DM];
  __shared__ float ps[4], pq[4];
  int tid = threadIdx.x, lane = tid & 63, wave = tid >> 6;
  for (int r = 0; r < 8; ++r) {
    float v0 = da[(size_t)r * DM + tid] + tbuf[(size_t)r * DM + tid];
    float v1 = da[(size_t)r * DM + tid + 256] + tbuf[(size_t)r * DM + tid + 256];
    ln_pair(v0, v1, tid, g2, b2ln, a[r], ps, pq);
  }
  int col = blockIdx.x * 4 + wave;
  bf16x8 w = *(const bf16x8*)&W1T[(size_t)col * DM + lane * 8];
  float acc[8];
#pragma unroll
  for (int r = 0; r < 8; ++r) acc[r] = dot8(w, &a[r][lane * 8]);
#pragma unroll
  for (int r = 0; r < 8; ++r)
    for (int o = 32; o > 0; o >>= 1) acc[r] += __shfl_xor(acc[r], o);
  if (lane == 0) {
    float bb = b1[col];
#pragma unroll
    for (int r = 0; r < 8; ++r) h[(size_t)r * DFF + col] = fmaxf(acc[r] + bb, 0.f);
  }
  if (blockIdx.x == 0) {
#pragma unroll
    for (int r = 0; r < 8; ++r) {
      xbuf[(size_t)r * DM + tid] = a[r][tid];
      xbuf[(size_t)r * DM + tid + 256] = a[r][tid + 256];
    }
  }
}

// df[r][col] = h[r] @ W2T[col] + b2[col]; 2 cols/block, 2 waves per col
__global__ __launch_bounds__(256) void dec_ffn2(
    const float* __restrict__ h, const __bf16* __restrict__ W2T,
    const float* __restrict__ b2, float* __restrict__ df) {
  __shared__ float red[4][8];
  int tid = threadIdx.x, lane = tid & 63, wave = tid >> 6;
  int c = wave >> 1, half = wave & 1;
  int col = blockIdx.x * 2 + c;
  int k0 = half * 1024 + lane * 8;
  bf16x8 w0 = *(const bf16x8*)&W2T[(size_t)col * DFF + k0];
  bf16x8 w1 = *(const bf16x8*)&W2T[(size_t)col * DFF + k0 + 512];
  float acc[8];
#pragma unroll
  for (int r = 0; r < 8; ++r) {
    float4 h0a = *(const float4*)&h[(size_t)r * DFF + k0];
    float4 h0b = *(const float4*)&h[(size_t)r * DFF + k0 + 4];
    float4 h1a = *(const float4*)&h[(size_t)r * DFF + k0 + 512];
    float4 h1b = *(const float4*)&h[(size_t)r * DFF + k0 + 516];
    float hh0[8] = {h0a.x, h0a.y, h0a.z, h0a.w, h0b.x, h0b.y, h0b.z, h0b.w};
    float hh1[8] = {h1a.x, h1a.y, h1a.z, h1a.w, h1b.x, h1b.y, h1b.z, h1b.w};
    acc[r] = dot8(w0, hh0) + dot8(w1, hh1);
  }
#pragma unroll
  for (int r = 0; r < 8; ++r)
    for (int o = 32; o > 0; o >>= 1) acc[r] += __shfl_xor(acc[r], o);
  if (lane == 0) {
#pragma unroll
    for (int r = 0; r < 8; ++r) red[wave][r] = acc[r];
  }
  __syncthreads();
  if (tid < 16) {
    int cc = tid >> 3, r = tid & 7;
    int ocol = blockIdx.x * 2 + cc;
    df[(size_t)r * DM + ocol] =
        red[cc * 2][r] + red[cc * 2 + 1][r] + b2[ocol];
  }
}

// out = LN3_5(df + x2) @ Wo + ob  (LN recomputed per block)
__global__ __launch_bounds__(256) void dec_outf(
    const float* __restrict__ df, const float* __restrict__ xbuf,
    const float* __restrict__ g3, const float* __restrict__ b3,
    const __bf16* __restrict__ WoT, const float* __restrict__ ob,
    float* __restrict__ out) {
  __shared__ float a[8][DM];
  __shared__ float ps[4], pq[4];
  int tid = threadIdx.x, lane = tid & 63, wave = tid >> 6;
  for (int r = 0; r < 8; ++r) {
    float v0 = df[(size_t)r * DM + tid] + xbuf[(size_t)r * DM + tid];
    float v1 = df[(size_t)r * DM + tid + 256] + xbuf[(size_t)r * DM + tid + 256];
    ln_pair(v0, v1, tid, g3, b3, a[r], ps, pq);
  }
  int col = blockIdx.x * 4 + wave;
  bf16x8 w = *(const bf16x8*)&WoT[(size_t)col * DM + lane * 8];
  float acc[8];
#pragma unroll
  for (int r = 0; r < 8; ++r) acc[r] = dot8(w, &a[r][lane * 8]);
#pragma unroll
  for (int r = 0; r < 8; ++r)
    for (int o = 32; o > 0; o >>= 1) acc[r] += __shfl_xor(acc[r], o);
  if (lane == 0) {
    float bb = ob[col];
#pragma unroll
    for (int r = 0; r < 8; ++r) out[(size_t)r * OUTD + col] = acc[r] + bb;
  }
}

// ---------------------------------------------------------------------------
extern "C" void kernel_launch(void* const* d_in, const int* in_sizes, int n_in,
                              void* d_out, int out_size, void* d_ws, size_t ws_size,
                              hipStream_t stream) {
  const int* x = (const int*)d_in[0];
  const int* target = (const int*)d_in[1];
  const float* in_emb = (const float*)d_in[2];
  const float* out_emb = (const float*)d_in[3];
  const float* enc_qkv_w = (const float*)d_in[4];
  const float* enc_qkv_b = (const float*)d_in[5];
  const float* enc_ln1_g = (const float*)d_in[6];
  const float* enc_ln1_b = (const float*)d_in[7];
  const float* enc_ffn1_w = (const float*)d_in[8];
  const float* enc_ffn1_b = (const float*)d_in[9];
  const float* enc_ffn2_w = (const float*)d_in[10];
  const float* enc_ffn2_b = (const float*)d_in[11];
  const float* enc_ln2_g = (const float*)d_in[12];
  const float* enc_ln2_b = (const float*)d_in[13];
  const float* dec_qkv1_w = (const float*)d_in[14];
  const float* dec_qkv1_b = (const float*)d_in[15];
  const float* dec_ln1_g = (const float*)d_in[16];
  const float* dec_ln1_b = (const float*)d_in[17];
  const float* dec_qkv2_w = (const float*)d_in[18];
  const float* dec_qkv2_b = (const float*)d_in[19];
  const float* dec_ln2_g = (const float*)d_in[20];
  const float* dec_ln2_b = (const float*)d_in[21];
  const float* dec_ffn1_w = (const float*)d_in[22];
  const float* dec_ffn1_b = (const float*)d_in[23];
  const float* dec_ffn2_w = (const float*)d_in[24];
  const float* dec_ffn2_b = (const float*)d_in[25];
  const float* dec_ln3_g = (const float*)d_in[26];
  const float* dec_ln3_b = (const float*)d_in[27];
  const float* out_w = (const float*)d_in[28];
  const float* out_b = (const float*)d_in[29];

  const long ACTL = (long)NB * SEQ * DM;           // 2M elems
  const int M = NB * SEQ;                           // 4096
  const long WQS = (long)DM * DM;
  const long WFS = (long)DM * DFF;

  char* p = (char*)d_ws;
  float* e = (float*)p;            p += ACTL * 4;
  float* tb = (float*)p;           p += ACTL * 4;
  float* pe = (float*)p;           p += (long)SEQ * DM * 4;
  float* dd = (float*)p;           p += NB * DM * 4;
  float* da = (float*)p;           p += NB * DM * 4;
  float* dh = (float*)p;           p += NB * DFF * 4;
  float* df = (float*)p;           p += NB * DM * 4;
  p = (char*)(((uintptr_t)p + 255) & ~(uintptr_t)255);
  __bf16* eb = (__bf16*)p;         p += ACTL * 2;
  __bf16* qkvb = (__bf16*)p;       p += 3 * ACTL * 2;   // Q,K; slice 2 = V^T
  __bf16* hbb = (__bf16*)p;        p += (long)M * DFF * 2;
  __bf16* kvb = (__bf16*)p;        p += 12L * ACTL * 2; // [layer][K,V][4096][512]
  __bf16* wtq = (__bf16*)p;        p += 18L * WQS * 2;
  __bf16* wtf1 = (__bf16*)p;       p += 6L * WFS * 2;
  __bf16* wtf2 = (__bf16*)p;       p += 6L * WFS * 2;
  __bf16* wtd = (__bf16*)p;        p += 18L * WQS * 2;  // dec_qkv2^T
  __bf16* wtd1 = (__bf16*)p;       p += 18L * WQS * 2;  // dec_qkv1 V-slices^T (6 used)
  __bf16* wf1t = (__bf16*)p;       p += 6L * WFS * 2;
  __bf16* wf2t = (__bf16*)p;       p += 6L * WFS * 2;
  __bf16* wot = (__bf16*)p;        p += (long)OUTD * DM * 2;

  __bf16* vtb = qkvb + 2 * ACTL;
  // split-K partial-1 for encoder FFN2: reuse kvb region (idle until the
  // KV gemm after the encoder loop)
  float* tb2 = (float*)kvb;
  // decoder scratch reuse: dd region holds t rows; pe region (dead after
  // embed_enc) holds x2 rows
  float* tbuf = dd;
  float* xbuf = pe;

  // ---- one-time prep (merged transposes: 5 dispatches total) ----
  pe_kernel<<<SEQ, 256, 0, stream>>>(pe);
  transpose_w3<<<dim3(16, 16, 42), 256, 0, stream>>>(
      enc_qkv_w, wtq, 18, dec_qkv2_w, wtd, 18, dec_qkv1_w, wtd1, 3, 2, DM, DM);
  transpose_w3<<<dim3(64, 16, 12), 256, 0, stream>>>(
      enc_ffn1_w, wtf1, 6, dec_ffn1_w, wf1t, 6, nullptr, nullptr, 0, 0, DM, DFF);
  transpose_w3<<<dim3(16, 64, 12), 256, 0, stream>>>(
      enc_ffn2_w, wtf2, 6, dec_ffn2_w, wf2t, 6, nullptr, nullptr, 0, 0, DFF, DM);
  transpose_ow<<<dim3(32, 16), 256, 0, stream>>>(out_w, wot);

  // ---- encoder ----
  embed_enc<<<(M * DM / 2) / 256, 256, 0, stream>>>(x, in_emb, pe, e, eb);
  for (int i = 0; i < NL; ++i) {
    mfma_gemm<64, 1, false, false, true, true, false><<<dim3(8, 32, 3), 256, 0, stream>>>(
        eb, wtq + (size_t)i * 3 * WQS, enc_qkv_b + (size_t)i * 3 * DM,
        nullptr, qkvb, vtb, M, DM, DM, WQS, DM, ACTL);
    attn_mfma<<<dim3(SEQ / 16, NB * NH), 256, 0, stream>>>(qkvb, vtb, tb);
    add_ln<true><<<M, 256, 0, stream>>>(tb, nullptr, e, nullptr,
                                        enc_ln1_g + i * DM, enc_ln1_b + i * DM,
                                        e, eb);
    mfma_gemm<64, 1, true, false, true, false, false><<<dim3(32, 32, 1), 256, 0, stream>>>(
        eb, wtf1 + (size_t)i * WFS, enc_ffn1_b + (size_t)i * DFF,
        nullptr, hbb, nullptr, M, DFF, DM, 0, 0, 0);
    mfma_gemm<64, 2, false, true, false, false, false><<<dim3(8, 32, 2), 256, 0, stream>>>(
        hbb, wtf2 + (size_t)i * WFS, enc_ffn2_b + (size_t)i * DM,
        tb, nullptr, nullptr, M, DM, DFF, 0, 0, (long)(tb2 - tb));
    add_ln<true><<<M, 256, 0, stream>>>(tb, tb2, e, nullptr,
                                        enc_ln2_g + i * DM, enc_ln2_b + i * DM,
                                        e, eb);
  }

  // ---- cross K/V for all 6 layers in one dispatch (bf16 out) ----
  mfma_gemm<64, 1, false, false, true, false, true><<<dim3(8, 32, 12), 256, 0, stream>>>(
      eb, wtd, dec_qkv2_b, nullptr, kvb, nullptr, M, DM, DM, WQS, DM, ACTL);

  // ---- decoder: 3 dispatches per layer ----
  for (int i = 0; i < NL; ++i) {
    const __bf16* Wv = wtd1 + (size_t)i * WQS;
    const float* bvp = dec_qkv1_b + ((size_t)i * 3 + 2) * DM;
    const __bf16* Wq = wtd + (size_t)i * 3 * WQS;
    const float* qbp = dec_qkv2_b + (size_t)i * 3 * DM;
    const __bf16* Kb = kvb + (size_t)i * 2 * ACTL;
    const __bf16* Vb = kvb + ((size_t)i * 2 + 1) * ACTL;
    if (i == 0)
      dec_attn<true><<<64, 256, 0, stream>>>(
          nullptr, nullptr, nullptr, nullptr, target, out_emb,
          Wv, bvp, dec_ln1_g + i * DM, dec_ln1_b + i * DM,
          Wq, qbp, Kb, Vb, da, tbuf);
    else
      dec_attn<false><<<64, 256, 0, stream>>>(
          df, xbuf, dec_ln3_g + (i - 1) * DM, dec_ln3_b + (i - 1) * DM,
          nullptr, nullptr,
          Wv, bvp, dec_ln1_g + i * DM, dec_ln1_b + i * DM,
          Wq, qbp, Kb, Vb, da, tbuf);
    dec_ffn1f<<<DFF / 4, 256, 0, stream>>>(
        da, tbuf, dec_ln2_g + i * DM, dec_ln2_b + i * DM,
        wf1t + (size_t)i * WFS, dec_ffn1_b + (size_t)i * DFF, dh, xbuf);
    dec_ffn2<<<DM / 2, 256, 0, stream>>>(
        dh, wf2t + (size_t)i * WFS, dec_ffn2_b + (size_t)i * DM, df);
  }

  // ---- output projection (LN3 + gemv + bias fused) ----
  dec_outf<<<OUTD / 4, 256, 0, stream>>>(df, xbuf, dec_ln3_g + 5 * DM,
                                         dec_ln3_b + 5 * DM, wot, out_b,
                                         (float*)d_out);
}